// Round 10
// baseline (180.922 us; speedup 1.0000x reference)
//
#include <hip/hip_runtime.h>

typedef short short8 __attribute__((ext_vector_type(8)));
typedef float f32x4 __attribute__((ext_vector_type(4)));
typedef unsigned short u16;
typedef unsigned int u32;

__device__ __forceinline__ u16 f2bf(float f) {
  union { float f; u32 u; } x; x.f = f;
  u32 u = x.u;
  u32 r = (u + 0x7FFFu + ((u >> 16) & 1u)) >> 16;
  return (u16)r;
}

__device__ __forceinline__ u32 cvtpk(float lo, float hi) {
  u32 r;
  asm("v_cvt_pk_bf16_f32 %0, %1, %2" : "=v"(r) : "v"(lo), "v"(hi));
  return r;
}

// ---- WB bf16-region offsets (u16 units) — decoder + bond weights only ----
#define OW2T   0        // bond W2^T      [256][256]
#define OW3TX  65536    // bond W3 padT   [16][256]
#define ODW1A  69632    // dW1[0:64]^T    [256][64]
#define ODW2   86016    // dW2^T          [256][256]
#define ODW3   151552   // dW3^T          [64][256]
#define OBPA   167936   // bpW1[0:64]^T   [256][64]  x0.125
#define OBPB   184320   // bpW1[64:128]^T [256][64]  x0.125
#define OREW1  200704   // reW1^T         [256][64]
#define OREW2  217088   // reW2 padT      [16][256]

// ====== k_prep1 (PROVEN r9): cond c2 + LDS-tiled coalesced transposes =================
__global__ void __launch_bounds__(512) k_prep1(
    const float* __restrict__ cnd, const float* __restrict__ ceW1,
    const float* __restrict__ ceb1, const float* __restrict__ ceW2,
    const float* __restrict__ ceb2, const float* __restrict__ dW1,
    const float* __restrict__ dW2, const float* __restrict__ dW3,
    const float* __restrict__ bpW1, const float* __restrict__ bpW2,
    const float* __restrict__ bpW3, const float* __restrict__ reW1,
    const float* __restrict__ reW2, float* __restrict__ c2g, u16* __restrict__ WB) {
  __shared__ float h[256], prf[256];
  __shared__ float T[64][65];
  int bid = blockIdx.x, t = threadIdx.x;
  if (bid < 64) {
    int b = bid;
    if (t < 256) {
      float c0 = cnd[b * 2 + 0], c1 = cnd[b * 2 + 1];
      h[t] = fmaxf(c0 * ceW1[t] + c1 * ceW1[256 + t] + ceb1[t], 0.f);
    }
    __syncthreads();
    int col = t & 255, g = t >> 8;
    float acc = 0.f;
    #pragma unroll 8
    for (int k = g * 128; k < g * 128 + 128; k++) acc += h[k] * ceW2[k * 256 + col];
    if (g) prf[col] = acc;
    __syncthreads();
    if (!g) c2g[b * 256 + col] = acc + prf[col] + ceb2[col];
    return;
  }
  int mb = bid - 64;  // 0..53
  if (mb >= 52) {
    if (t < 256) {
      const float* s = (mb == 52) ? reW2 : bpW3;
      u16* d = WB + ((mb == 52) ? OREW2 : OW3TX);
      #pragma unroll
      for (int c = 0; c < 16; c++) {
        float v = (c < 4) ? s[t * 4 + c] : 0.f;
        d[c * 256 + t] = f2bf(v);
      }
    }
    return;
  }
  const float* src; u16* dst; int sld, dld, tr, tc; float sc = 1.f;
  if (mb < 4)       { src = dW1;           dst = WB + ODW1A; sld = 256; dld = 64;  tr = 0;            tc = mb;          }
  else if (mb < 20) { int e = mb - 4;  src = dW2;  dst = WB + ODW2; sld = 256; dld = 256; tr = e >> 2; tc = e & 3; }
  else if (mb < 24) { int e = mb - 20; src = dW3;  dst = WB + ODW3; sld = 64;  dld = 256; tr = e;      tc = 0;     }
  else if (mb < 28) { int e = mb - 24; src = bpW1; dst = WB + OBPA; sld = 256; dld = 64;  tr = 0;      tc = e; sc = 0.125f; }
  else if (mb < 32) { int e = mb - 28; src = bpW1 + 64 * 256; dst = WB + OBPB; sld = 256; dld = 64; tr = 0; tc = e; sc = 0.125f; }
  else if (mb < 36) { int e = mb - 32; src = reW1; dst = WB + OREW1; sld = 256; dld = 64; tr = 0;      tc = e;     }
  else              { int e = mb - 36; src = bpW2; dst = WB + OW2T; sld = 256; dld = 256; tr = e >> 2; tc = e & 3; }
  int rl = t >> 6, cl = t & 63;
  #pragma unroll
  for (int it = 0; it < 8; it++) {
    int r = it * 8 + rl;
    T[r][cl] = src[(tr * 64 + r) * sld + tc * 64 + cl] * sc;
  }
  __syncthreads();
  #pragma unroll
  for (int it = 0; it < 8; it++) {
    int c2_ = it * 8 + rl;
    dst[(tc * 64 + c2_) * dld + tr * 64 + cl] = f2bf(T[cl][c2_]);
  }
}

// ====== k_prep2 (PROVEN r9): ctf/ctv from c2 ==========================================
__global__ void __launch_bounds__(512) k_prep2(
    const float* __restrict__ c2g, const float* __restrict__ bpW1,
    const float* __restrict__ bpb1, const float* __restrict__ dW1,
    const float* __restrict__ db1, float* __restrict__ ctf, float* __restrict__ ctv) {
  __shared__ float c2s[256], prf[256], prv[256];
  int b = blockIdx.x, t = threadIdx.x;
  if (t < 256) c2s[t] = c2g[b * 256 + t];
  __syncthreads();
  int col = t & 255, g = t >> 8;
  float af = 0.f, av = 0.f;
  #pragma unroll 4
  for (int k = g * 128; k < g * 128 + 128; k++) {
    float cv = c2s[k];
    af += cv * bpW1[(128 + k) * 256 + col];
    av += cv * dW1[(64 + k) * 256 + col];
  }
  if (g) { prf[col] = af; prv[col] = av; }
  __syncthreads();
  if (!g) {
    ctf[b * 256 + col] = af + prf[col] + bpb1[col];
    ctv[b * 256 + col] = av + prv[col] + db1[col];
  }
}

// ====== k_gc1: ah1 = adj @ relu((adj@x)@gc1W + b1), fused per (cg,b) ==================
__global__ void __launch_bounds__(512) k_gc1(
    const float* __restrict__ adj, const float* __restrict__ x,
    const float* __restrict__ W1, const float* __restrict__ b1,
    float* __restrict__ out) {
  __shared__ float adj_s[64 * 64];
  __shared__ float x_s[64 * 64];
  __shared__ float ax_s[64 * 64];
  __shared__ float h_s[64 * 64];
  int cg = blockIdx.x, b = blockIdx.y, t = threadIdx.x;
  const float* A = adj + b * 4096;
  const float* X = x + b * 4096;
  for (int e = t; e < 4096; e += 512) { adj_s[e] = A[e]; x_s[e] = X[e]; }
  __syncthreads();
  int c = t & 63, rg = t >> 6;
  // ax = adj @ x
  {
    float acc[8];
    #pragma unroll
    for (int m = 0; m < 8; m++) acc[m] = 0.f;
    #pragma unroll 8
    for (int j = 0; j < 64; j++) {
      float xv = x_s[j * 64 + c];
      #pragma unroll
      for (int m = 0; m < 8; m++) acc[m] += adj_s[(m * 8 + rg) * 64 + j] * xv;
    }
    #pragma unroll
    for (int m = 0; m < 8; m++) ax_s[(m * 8 + rg) * 64 + c] = acc[m];
  }
  __syncthreads();
  // h = relu(ax @ W1[:, cg*64..] + b1)
  {
    float bv = b1[cg * 64 + c];
    float acc[8];
    #pragma unroll
    for (int m = 0; m < 8; m++) acc[m] = bv;
    #pragma unroll 8
    for (int k = 0; k < 64; k++) {
      float wv = W1[k * 256 + cg * 64 + c];
      #pragma unroll
      for (int m = 0; m < 8; m++) acc[m] += ax_s[(m * 8 + rg) * 64 + k] * wv;
    }
    #pragma unroll
    for (int m = 0; m < 8; m++) h_s[(m * 8 + rg) * 64 + c] = fmaxf(acc[m], 0.f);
  }
  __syncthreads();
  // out = adj @ h
  {
    float acc[8];
    #pragma unroll
    for (int m = 0; m < 8; m++) acc[m] = 0.f;
    #pragma unroll 8
    for (int j = 0; j < 64; j++) {
      float hv = h_s[j * 64 + c];
      #pragma unroll
      for (int m = 0; m < 8; m++) acc[m] += adj_s[(m * 8 + rg) * 64 + j] * hv;
    }
    float* O = out + b * 64 * 256 + cg * 64;
    #pragma unroll
    for (int m = 0; m < 8; m++) O[(m * 8 + rg) * 256 + c] = acc[m];
  }
}

// ====== k_linadj: ah2 = adj @ relu(in@gc2W + b2), fused, 2-pass in_s staging ==========
__global__ void __launch_bounds__(512) k_linadj(
    const float* __restrict__ adj, const float* __restrict__ in,
    const float* __restrict__ W, const float* __restrict__ bias,
    float* __restrict__ out) {
  __shared__ float adj_s[64 * 64];
  __shared__ float in_s[32 * 256];
  __shared__ float h_s[64 * 64];
  int cg = blockIdx.x, b = blockIdx.y, t = threadIdx.x;
  const float* A = adj + b * 4096;
  for (int e = t; e < 4096; e += 512) adj_s[e] = A[e];
  int c = t & 63, rg = t >> 6;
  float bv = bias[cg * 64 + c];
  #pragma unroll
  for (int half = 0; half < 2; half++) {
    if (half) __syncthreads();  // previous-half readers done before overwrite
    const float* I = in + (b * 64 + half * 32) * 256;
    for (int e = t; e < 32 * 256; e += 512) in_s[e] = I[e];
    __syncthreads();
    float acc[4];
    #pragma unroll
    for (int m = 0; m < 4; m++) acc[m] = bv;
    #pragma unroll 8
    for (int k = 0; k < 256; k++) {
      float wv = W[k * 256 + cg * 64 + c];
      #pragma unroll
      for (int m = 0; m < 4; m++) acc[m] += in_s[(m * 8 + rg) * 256 + k] * wv;
    }
    #pragma unroll
    for (int m = 0; m < 4; m++)
      h_s[(half * 32 + m * 8 + rg) * 64 + c] = fmaxf(acc[m], 0.f);
  }
  __syncthreads();
  {
    float acc[8];
    #pragma unroll
    for (int m = 0; m < 8; m++) acc[m] = 0.f;
    #pragma unroll 8
    for (int j = 0; j < 64; j++) {
      float hv = h_s[j * 64 + c];
      #pragma unroll
      for (int m = 0; m < 8; m++) acc[m] += adj_s[(m * 8 + rg) * 64 + j] * hv;
    }
    float* O = out + b * 64 * 256 + cg * 64;
    #pragma unroll
    for (int m = 0; m < 8; m++) O[(m * 8 + rg) * 256 + c] = acc[m];
  }
}

// ---------------- mu / logvar heads; 512 threads (PROVEN r4) --------------------------
__global__ void k_mulv(const float* __restrict__ in, const float* __restrict__ Wmu,
                       const float* __restrict__ bmu, const float* __restrict__ Wlv,
                       const float* __restrict__ blv, float* __restrict__ mu_out,
                       float* __restrict__ lv_out) {
  __shared__ float in_s[16 * 256];
  __shared__ float part[8 * 16 * 64];
  int t = threadIdx.x, r0 = blockIdx.x * 16;
  for (int e = t; e < 4096; e += 512) in_s[e] = in[r0 * 256 + e];
  __syncthreads();
  int c = t & 63, g = t >> 6;
  int sel = g >> 2, kq = g & 3;
  const float* W = sel ? Wlv : Wmu;
  float acc[16];
  #pragma unroll
  for (int r = 0; r < 16; r++) acc[r] = 0.f;
  #pragma unroll 4
  for (int k = kq * 64; k < kq * 64 + 64; k++) {
    float w = W[k * 64 + c];
    #pragma unroll
    for (int r = 0; r < 16; r++) acc[r] += in_s[r * 256 + k] * w;
  }
  #pragma unroll
  for (int r = 0; r < 16; r++) part[(g * 16 + r) * 64 + c] = acc[r];
  __syncthreads();
  if (t < 128) {
    int cc = t & 63, s2 = t >> 6;
    const float* bb = s2 ? blv : bmu;
    float* O = s2 ? lv_out : mu_out;
    float bv = bb[cc];
    #pragma unroll
    for (int r = 0; r < 16; r++) {
      float v = bv;
      #pragma unroll
      for (int q = 0; q < 4; q++) v += part[((s2 * 4 + q) * 16 + r) * 64 + cc];
      O[(r0 + r) * 64 + cc] = v;
    }
  }
}

// =============== NT GEMM core (PROVEN r6-r9) ==========================================
template <int KK, int WU, int WV, bool UG, bool VG, int ULEN, int VLEN>
__device__ __forceinline__ void mmrun(const u16* __restrict__ Up, int Uoff,
                                      const u16* __restrict__ Vp, int Voff,
                                      const char* lds, int ut0, int vt0, int lr, int lk,
                                      f32x4 (&acc)[WU][WV]) {
  #pragma unroll
  for (int kk = 0; kk < KK; kk++) {
    short8 uf[WU], vf[WV];
    #pragma unroll
    for (int i = 0; i < WU; i++) {
      int row = (ut0 + i) * 16 + lr;
      if constexpr (UG) {
        uf[i] = *(const short8*)(Up + row * ULEN + kk * 32 + lk * 8);
      } else {
        int byt = Uoff + row * (ULEN * 2) + kk * 64 + lk * 16;
        byt ^= (row & 7) << 4;
        uf[i] = *(const short8*)(lds + byt);
      }
    }
    #pragma unroll
    for (int j = 0; j < WV; j++) {
      int row = (vt0 + j) * 16 + lr;
      if constexpr (VG) {
        vf[j] = *(const short8*)(Vp + row * VLEN + kk * 32 + lk * 8);
      } else {
        int byt = Voff + row * (VLEN * 2) + kk * 64 + lk * 16;
        byt ^= (row & 7) << 4;
        vf[j] = *(const short8*)(lds + byt);
      }
    }
    #pragma unroll
    for (int i = 0; i < WU; i++)
      #pragma unroll
      for (int j = 0; j < WV; j++)
        acc[i][j] = __builtin_amdgcn_mfma_f32_16x16x32_bf16(uf[i], vf[j], acc[i][j], 0, 0, 0);
  }
}

__device__ __forceinline__ void st64(char* lds, int off, int rowlen, int crow, int ccol0,
                                     float a0, float a1, float a2, float a3) {
  uint2 pk; pk.x = cvtpk(a0, a1); pk.y = cvtpk(a2, a3);
  int byt = off + crow * (rowlen * 2) + ccol0 * 2;
  byt ^= (crow & 7) << 4;
  *(uint2*)(lds + byt) = pk;
}

template <int WU, int WV>
__device__ __forceinline__ void zacc(f32x4 (&acc)[WU][WV]) {
  #pragma unroll
  for (int i = 0; i < WU; i++)
    #pragma unroll
    for (int j = 0; j < WV; j++) acc[i][j] = (f32x4){0.f, 0.f, 0.f, 0.f};
}

// =============== k_chain2 (PROVEN r6): decoder, bf16 MFMA =============================
__global__ void __launch_bounds__(1024) k_chain2(
    const u16* __restrict__ WB, const float* __restrict__ mu_g,
    const float* __restrict__ ctv, const float* __restrict__ ctf,
    const float* __restrict__ db2, const float* __restrict__ db3,
    const float* __restrict__ reb1, const float* __restrict__ reb2,
    float* __restrict__ af_out, float* __restrict__ val_out,
    float* __restrict__ P, float* __restrict__ Q) {
  __shared__ char L[65536];
  constexpr int S2 = 0, S3 = 32768;
  int b = blockIdx.x, t = threadIdx.x;
  int w = t >> 6, lane = t & 63, lr = lane & 15, lk = lane >> 4;

  {
    int r = t >> 4, c0 = (t & 15) * 4;
    float4 v = *(const float4*)(mu_g + ((b * 64 + r) * 64 + c0));
    st64(L, S3, 64, r, c0, v.x, v.y, v.z, v.w);
  }
  __syncthreads();
  {
    f32x4 a[2][2]; zacc(a);
    int ut0 = (w & 7) * 2, vt0 = (w >> 3) * 2;
    mmrun<2, 2, 2, true, false, 64, 64>(WB + ODW1A, 0, WB, S3, L, ut0, vt0, lr, lk, a);
    #pragma unroll
    for (int j = 0; j < 2; j++) {
      int crow = (vt0 + j) * 16 + lr;
      #pragma unroll
      for (int i = 0; i < 2; i++) {
        int cc = (ut0 + i) * 16 + lk * 4;
        float4 cv = *(const float4*)(ctv + b * 256 + cc);
        st64(L, S2, 256, crow, cc, fmaxf(a[i][j][0] + cv.x, 0.f), fmaxf(a[i][j][1] + cv.y, 0.f),
             fmaxf(a[i][j][2] + cv.z, 0.f), fmaxf(a[i][j][3] + cv.w, 0.f));
      }
    }
  }
  __syncthreads();
  {
    f32x4 a[2][2]; zacc(a);
    int ut0 = (w & 7) * 2, vt0 = (w >> 3) * 2;
    mmrun<8, 2, 2, true, false, 256, 256>(WB + ODW2, 0, WB, S2, L, ut0, vt0, lr, lk, a);
    #pragma unroll
    for (int j = 0; j < 2; j++) {
      int crow = (vt0 + j) * 16 + lr;
      #pragma unroll
      for (int i = 0; i < 2; i++) {
        int cc = (ut0 + i) * 16 + lk * 4;
        float4 bv = *(const float4*)(db2 + cc);
        st64(L, S3, 256, crow, cc, fmaxf(a[i][j][0] + bv.x, 0.f), fmaxf(a[i][j][1] + bv.y, 0.f),
             fmaxf(a[i][j][2] + bv.z, 0.f), fmaxf(a[i][j][3] + bv.w, 0.f));
      }
    }
  }
  __syncthreads();
  {
    f32x4 a[1][1]; zacc(a);
    int ut = w & 3, vt = w >> 2;
    mmrun<8, 1, 1, true, false, 256, 256>(WB + ODW3, 0, WB, S3, L, ut, vt, lr, lk, a);
    int crow = vt * 16 + lr, cc = ut * 16 + lk * 4;
    float4 bv = *(const float4*)(db3 + cc);
    float s0 = 1.f / (1.f + expf(-(a[0][0][0] + bv.x)));
    float s1 = 1.f / (1.f + expf(-(a[0][0][1] + bv.y)));
    float s2 = 1.f / (1.f + expf(-(a[0][0][2] + bv.z)));
    float s3 = 1.f / (1.f + expf(-(a[0][0][3] + bv.w)));
    *(float4*)(af_out + ((b * 64 + crow) * 64 + cc)) =
        make_float4(s0 * 0.125f, s1 * 0.125f, s2 * 0.125f, s3 * 0.125f);
    st64(L, S2, 64, crow, cc, s0, s1, s2, s3);
  }
  __syncthreads();
  {
    f32x4 a[2][4]; zacc(a);
    int ut0 = (w & 7) * 2;
    int sel = w >> 3;
    const u16* Up = WB + (sel ? OBPB : OBPA);
    mmrun<2, 2, 4, true, false, 64, 64>(Up, 0, WB, S2, L, ut0, 0, lr, lk, a);
    float* out = sel ? Q : P;
    #pragma unroll
    for (int i = 0; i < 2; i++) {
      int cc = (ut0 + i) * 16 + lk * 4;
      float4 cv = make_float4(0.f, 0.f, 0.f, 0.f);
      if (sel == 0) cv = *(const float4*)(ctf + b * 256 + cc);
      #pragma unroll
      for (int j = 0; j < 4; j++) {
        int crow = j * 16 + lr;
        *(float4*)(out + ((b * 64 + crow) * 256 + cc)) =
            make_float4(a[i][j][0] + cv.x, a[i][j][1] + cv.y, a[i][j][2] + cv.z, a[i][j][3] + cv.w);
      }
    }
  }
  {
    f32x4 a[2][2]; zacc(a);
    int ut0 = (w & 7) * 2, vt0 = (w >> 3) * 2;
    mmrun<2, 2, 2, true, false, 64, 64>(WB + OREW1, 0, WB, S2, L, ut0, vt0, lr, lk, a);
    #pragma unroll
    for (int j = 0; j < 2; j++) {
      int crow = (vt0 + j) * 16 + lr;
      #pragma unroll
      for (int i = 0; i < 2; i++) {
        int cc = (ut0 + i) * 16 + lk * 4;
        float4 bv = *(const float4*)(reb1 + cc);
        st64(L, S3, 256, crow, cc, fmaxf(a[i][j][0] + bv.x, 0.f), fmaxf(a[i][j][1] + bv.y, 0.f),
             fmaxf(a[i][j][2] + bv.z, 0.f), fmaxf(a[i][j][3] + bv.w, 0.f));
      }
    }
  }
  __syncthreads();
  if (w < 4) {
    f32x4 a[1][1]; zacc(a);
    mmrun<8, 1, 1, true, false, 256, 256>(WB + OREW2, 0, WB, S3, L, 0, w, lr, lk, a);
    if (lk == 0) {
      float4 rb = *(const float4*)reb2;
      float v0 = 4.f / (1.f + expf(-(a[0][0][0] + rb.x)));
      float v1 = 4.f / (1.f + expf(-(a[0][0][1] + rb.y)));
      float v2 = 4.f / (1.f + expf(-(a[0][0][2] + rb.z)));
      float v3 = 4.f / (1.f + expf(-(a[0][0][3] + rb.w)));
      *(float4*)(val_out + (b * 64 + w * 16 + lr) * 4) = make_float4(v0, v1, v2, v3);
    }
  }
}

// ===== k_bond v6: wave -> (tile, 64-col group); halved LDS traffic in GEMM1 ===========
__global__ void __launch_bounds__(512, 4) k_bond(
    const float* __restrict__ P, const float* __restrict__ Q,
    const u16* __restrict__ W2T, const float* __restrict__ b2,
    const u16* __restrict__ W3Tx, const float* __restrict__ b3,
    float* __restrict__ bp_out) {
  __shared__ u16 G[2 * 64 * 256];  // 64 KB: two XOR-swizzled 64x256 bf16 tiles
  int flat = blockIdx.x;
  int xcd = flat & 7, rest = flat >> 3;
  int b = xcd * 8 + (rest >> 5);
  int i0 = (rest & 31) * 2;
  int t = threadIdx.x;
  int lane = t & 63, w = t >> 6;
  int lr = lane & 15, lk = lane >> 4;

  // ---- build both G tiles (PROVEN r8) ----
  {
    int colg = t & 63, rq = t >> 6;
    const float* Pb = P + (b * 64 + i0) * 256 + colg * 4;
    float4 p0 = *(const float4*)(Pb);
    float4 p1 = *(const float4*)(Pb + 256);
    const float* Qb = Q + b * 64 * 256;
    #pragma unroll
    for (int r = rq * 8; r < rq * 8 + 8; r++) {
      float4 q4 = *(const float4*)(Qb + r * 256 + colg * 4);
      int byt = (r * 512 + colg * 8) ^ ((r & 7) << 4);
      uint2 pk0, pk1;
      pk0.x = cvtpk(fmaxf(p0.x + q4.x, 0.f), fmaxf(p0.y + q4.y, 0.f));
      pk0.y = cvtpk(fmaxf(p0.z + q4.z, 0.f), fmaxf(p0.w + q4.w, 0.f));
      pk1.x = cvtpk(fmaxf(p1.x + q4.x, 0.f), fmaxf(p1.y + q4.y, 0.f));
      pk1.y = cvtpk(fmaxf(p1.z + q4.z, 0.f), fmaxf(p1.w + q4.w, 0.f));
      *(uint2*)((char*)G + byt) = pk0;
      *(uint2*)((char*)G + 32768 + byt) = pk1;
    }
  }
  __syncthreads();

  // ---- GEMM1: wave -> (tl = w&1, cg = w>>1); ni=4 cols x mi=4 rows; A reused 4x ----
  int tl = w & 1, cg = w >> 1;
  int tlo = tl * 32768;
  f32x4 acc[4][4];  // [ni][mi]
  #pragma unroll
  for (int ni = 0; ni < 4; ni++)
    #pragma unroll
    for (int mi = 0; mi < 4; mi++) acc[ni][mi] = (f32x4){0.f, 0.f, 0.f, 0.f};

  const u16* Wl = W2T + (cg * 64 + lr) * 256 + lk * 8;
  short8 bwc[4];
  #pragma unroll
  for (int ni = 0; ni < 4; ni++) bwc[ni] = *(const short8*)(Wl + ni * 16 * 256);
  for (int kk = 0; kk < 8; kk++) {
    int kn = (kk + 1) & 7;
    short8 bwn[4];
    #pragma unroll
    for (int ni = 0; ni < 4; ni++) bwn[ni] = *(const short8*)(Wl + ni * 16 * 256 + kn * 32);
    __builtin_amdgcn_s_setprio(1);
    #pragma unroll
    for (int mi = 0; mi < 4; mi++) {
      int row = mi * 16 + lr;
      int byt = ((row * 512 + kk * 64 + lk * 16) ^ ((row & 7) << 4)) + tlo;
      short8 a = *(const short8*)((const char*)G + byt);
      #pragma unroll
      for (int ni = 0; ni < 4; ni++)
        acc[ni][mi] = __builtin_amdgcn_mfma_f32_16x16x32_bf16(bwc[ni], a, acc[ni][mi], 0, 0, 0);
    }
    __builtin_amdgcn_s_setprio(0);
    #pragma unroll
    for (int ni = 0; ni < 4; ni++) bwc[ni] = bwn[ni];
  }
  __syncthreads();

  // ---- writeback g2 (bias+relu) bf16; wave covers its 64 cols of its tile ----
  #pragma unroll
  for (int ni = 0; ni < 4; ni++) {
    int col0 = cg * 64 + ni * 16 + lk * 4;
    float4 bb = *(const float4*)(b2 + col0);
    #pragma unroll
    for (int mi = 0; mi < 4; mi++) {
      int grow = mi * 16 + lr;
      uint2 pk;
      pk.x = cvtpk(fmaxf(acc[ni][mi][0] + bb.x, 0.f), fmaxf(acc[ni][mi][1] + bb.y, 0.f));
      pk.y = cvtpk(fmaxf(acc[ni][mi][2] + bb.z, 0.f), fmaxf(acc[ni][mi][3] + bb.w, 0.f));
      int byt = ((grow * 512 + col0 * 2) ^ ((grow & 7) << 4)) + tlo;
      *(uint2*)((char*)G + byt) = pk;
    }
  }
  __syncthreads();

  // ---- GEMM2: wave does K-slice [cg*64, cg*64+64) of its tile ----
  f32x4 acc2[4];
  #pragma unroll
  for (int mi = 0; mi < 4; mi++) acc2[mi] = (f32x4){0.f, 0.f, 0.f, 0.f};
  #pragma unroll
  for (int kk2 = 0; kk2 < 2; kk2++) {
    short8 bw2 = *(const short8*)(W3Tx + lr * 256 + cg * 64 + kk2 * 32 + lk * 8);
    #pragma unroll
    for (int mi = 0; mi < 4; mi++) {
      int row = mi * 16 + lr;
      int kb = (cg * 64 + kk2 * 32 + lk * 8) * 2;
      int byt = ((row * 512 + kb) ^ ((row & 7) << 4)) + tlo;
      short8 a = *(const short8*)((const char*)G + byt);
      acc2[mi] = __builtin_amdgcn_mfma_f32_16x16x32_bf16(a, bw2, acc2[mi], 0, 0, 0);
    }
  }
  __syncthreads();  // G reads done; alias 8KB of G as float partials [tl][cg][row][4]
  float* pf = (float*)G;
  if (lr < 4) {
    #pragma unroll
    for (int mi = 0; mi < 4; mi++)
      #pragma unroll
      for (int rg = 0; rg < 4; rg++) {
        int row = mi * 16 + lk * 4 + rg;
        pf[((tl * 4 + cg) * 64 + row) * 4 + lr] = acc2[mi][rg];
      }
  }
  __syncthreads();

  // ---- softmax: 512 threads = 2 tiles x 64 rows x 4 cols; sum 4 cg partials ----
  {
    int tl2 = t >> 8, idx = t & 255;
    int r = idx >> 2, c = idx & 3;
    float lv = b3[c];
    #pragma unroll
    for (int cq = 0; cq < 4; cq++) lv += pf[((tl2 * 4 + cq) * 64 + r) * 4 + c];
    float m = fmaxf(lv, __shfl_xor(lv, 1));
    m = fmaxf(m, __shfl_xor(m, 2));
    float e = expf(lv - m);
    float s = e + __shfl_xor(e, 1);
    s += __shfl_xor(s, 2);
    bp_out[((b * 64 + i0 + tl2) * 64 + r) * 4 + c] = e / s;
  }
}

extern "C" void kernel_launch(void* const* d_in, const int* in_sizes, int n_in,
                              void* d_out, int out_size, void* d_ws, size_t ws_size,
                              hipStream_t stream) {
  const float* x    = (const float*)d_in[0];
  const float* adj  = (const float*)d_in[1];
  const float* cnd  = (const float*)d_in[2];
  const float* gc1W = (const float*)d_in[3];
  const float* gc1b = (const float*)d_in[4];
  const float* gc2W = (const float*)d_in[5];
  const float* gc2b = (const float*)d_in[6];
  const float* gmuW = (const float*)d_in[7];
  const float* gmub = (const float*)d_in[8];
  const float* glvW = (const float*)d_in[9];
  const float* glvb = (const float*)d_in[10];
  const float* ceW1 = (const float*)d_in[11];
  const float* ceb1 = (const float*)d_in[12];
  const float* ceW2 = (const float*)d_in[13];
  const float* ceb2 = (const float*)d_in[14];
  const float* dW1  = (const float*)d_in[15];
  const float* db1  = (const float*)d_in[16];
  const float* dW2  = (const float*)d_in[17];
  const float* db2  = (const float*)d_in[18];
  const float* dW3  = (const float*)d_in[19];
  const float* db3  = (const float*)d_in[20];
  // d_in[21..24] (at_*) are dead: mean(softmax) == 1/8 exactly
  const float* bpW1 = (const float*)d_in[25];
  const float* bpb1 = (const float*)d_in[26];
  const float* bpW2 = (const float*)d_in[27];
  const float* bpb2 = (const float*)d_in[28];
  const float* bpW3 = (const float*)d_in[29];
  const float* bpb3 = (const float*)d_in[30];
  const float* reW1 = (const float*)d_in[31];
  const float* reb1 = (const float*)d_in[32];
  const float* reW2 = (const float*)d_in[33];
  const float* reb2 = (const float*)d_in[34];

  float* out = (float*)d_out;
  float* af_out  = out;            // [64,64,64]
  float* bp_out  = out + 262144;   // [64,64,64,4]
  float* val_out = out + 1310720;  // [64,64,4]
  float* mu_out  = out + 1327104;  // [64,64,64]
  float* lv_out  = out + 1589248;  // [64,64,64]

  float* ws   = (float*)d_ws;
  float* ctf  = ws;                 // 16384
  float* ctv  = ws + 16384;         // 16384
  float* c2g  = ws + 32768;         // 16384
  float* buf1 = ws + 49152;         // 1048576  (ah1)
  float* buf2 = buf1 + 1048576;     // 1048576  (P)
  float* buf3 = buf2 + 1048576;     // 1048576  (ah2; later Q)
  u16*   WB   = (u16*)(buf3 + 1048576);  // 221184 u16

  k_prep1<<<118, 512, 0, stream>>>(cnd, ceW1, ceb1, ceW2, ceb2, dW1, dW2, dW3,
                                   bpW1, bpW2, bpW3, reW1, reW2, c2g, WB);
  k_prep2<<<64, 512, 0, stream>>>(c2g, bpW1, bpb1, dW1, db1, ctf, ctv);
  k_gc1<<<dim3(4, 64), 512, 0, stream>>>(adj, x, gc1W, gc1b, buf1);        // ah1
  k_linadj<<<dim3(4, 64), 512, 0, stream>>>(adj, buf1, gc2W, gc2b, buf3);  // ah2
  k_mulv<<<256, 512, 0, stream>>>(buf3, gmuW, gmub, glvW, glvb, mu_out, lv_out);
  k_chain2<<<64, 1024, 0, stream>>>(WB, mu_out, ctv, ctf, db2, db3, reb1, reb2,
                                    af_out, val_out, buf2, buf3);          // P=buf2 Q=buf3
  k_bond<<<2048, 512, 0, stream>>>(buf2, buf3, WB + OW2T, bpb2, WB + OW3TX, bpb3, bp_out);
}

// Round 11
// 161.180 us; speedup vs baseline: 1.1225x; 1.1225x over previous
//
#include <hip/hip_runtime.h>

typedef short short8 __attribute__((ext_vector_type(8)));
typedef float f32x4 __attribute__((ext_vector_type(4)));
typedef unsigned short u16;
typedef unsigned int u32;

__device__ __forceinline__ u16 f2bf(float f) {
  union { float f; u32 u; } x; x.f = f;
  u32 u = x.u;
  u32 r = (u + 0x7FFFu + ((u >> 16) & 1u)) >> 16;
  return (u16)r;
}

__device__ __forceinline__ u32 cvtpk(float lo, float hi) {
  u32 r;
  asm("v_cvt_pk_bf16_f32 %0, %1, %2" : "=v"(r) : "v"(lo), "v"(hi));
  return r;
}

// ---- WB bf16-region offsets (u16 units) — decoder + bond weights only ----
#define OW2T   0        // bond W2^T      [256][256]
#define OW3TX  65536    // bond W3 padT   [16][256]
#define ODW1A  69632    // dW1[0:64]^T    [256][64]
#define ODW2   86016    // dW2^T          [256][256]
#define ODW3   151552   // dW3^T          [64][256]
#define OBPA   167936   // bpW1[0:64]^T   [256][64]  x0.125
#define OBPB   184320   // bpW1[64:128]^T [256][64]  x0.125
#define OREW1  200704   // reW1^T         [256][64]
#define OREW2  217088   // reW2 padT      [16][256]

// ====== k_prep1 (PROVEN r9): cond c2 + LDS-tiled coalesced transposes =================
__global__ void __launch_bounds__(512) k_prep1(
    const float* __restrict__ cnd, const float* __restrict__ ceW1,
    const float* __restrict__ ceb1, const float* __restrict__ ceW2,
    const float* __restrict__ ceb2, const float* __restrict__ dW1,
    const float* __restrict__ dW2, const float* __restrict__ dW3,
    const float* __restrict__ bpW1, const float* __restrict__ bpW2,
    const float* __restrict__ bpW3, const float* __restrict__ reW1,
    const float* __restrict__ reW2, float* __restrict__ c2g, u16* __restrict__ WB) {
  __shared__ float h[256], prf[256];
  __shared__ float T[64][65];
  int bid = blockIdx.x, t = threadIdx.x;
  if (bid < 64) {
    int b = bid;
    if (t < 256) {
      float c0 = cnd[b * 2 + 0], c1 = cnd[b * 2 + 1];
      h[t] = fmaxf(c0 * ceW1[t] + c1 * ceW1[256 + t] + ceb1[t], 0.f);
    }
    __syncthreads();
    int col = t & 255, g = t >> 8;
    float acc = 0.f;
    #pragma unroll 8
    for (int k = g * 128; k < g * 128 + 128; k++) acc += h[k] * ceW2[k * 256 + col];
    if (g) prf[col] = acc;
    __syncthreads();
    if (!g) c2g[b * 256 + col] = acc + prf[col] + ceb2[col];
    return;
  }
  int mb = bid - 64;  // 0..53
  if (mb >= 52) {
    if (t < 256) {
      const float* s = (mb == 52) ? reW2 : bpW3;
      u16* d = WB + ((mb == 52) ? OREW2 : OW3TX);
      #pragma unroll
      for (int c = 0; c < 16; c++) {
        float v = (c < 4) ? s[t * 4 + c] : 0.f;
        d[c * 256 + t] = f2bf(v);
      }
    }
    return;
  }
  const float* src; u16* dst; int sld, dld, tr, tc; float sc = 1.f;
  if (mb < 4)       { src = dW1;           dst = WB + ODW1A; sld = 256; dld = 64;  tr = 0;            tc = mb;          }
  else if (mb < 20) { int e = mb - 4;  src = dW2;  dst = WB + ODW2; sld = 256; dld = 256; tr = e >> 2; tc = e & 3; }
  else if (mb < 24) { int e = mb - 20; src = dW3;  dst = WB + ODW3; sld = 64;  dld = 256; tr = e;      tc = 0;     }
  else if (mb < 28) { int e = mb - 24; src = bpW1; dst = WB + OBPA; sld = 256; dld = 64;  tr = 0;      tc = e; sc = 0.125f; }
  else if (mb < 32) { int e = mb - 28; src = bpW1 + 64 * 256; dst = WB + OBPB; sld = 256; dld = 64; tr = 0; tc = e; sc = 0.125f; }
  else if (mb < 36) { int e = mb - 32; src = reW1; dst = WB + OREW1; sld = 256; dld = 64; tr = 0;      tc = e;     }
  else              { int e = mb - 36; src = bpW2; dst = WB + OW2T; sld = 256; dld = 256; tr = e >> 2; tc = e & 3; }
  int rl = t >> 6, cl = t & 63;
  #pragma unroll
  for (int it = 0; it < 8; it++) {
    int r = it * 8 + rl;
    T[r][cl] = src[(tr * 64 + r) * sld + tc * 64 + cl] * sc;
  }
  __syncthreads();
  #pragma unroll
  for (int it = 0; it < 8; it++) {
    int c2_ = it * 8 + rl;
    dst[(tc * 64 + c2_) * dld + tr * 64 + cl] = f2bf(T[cl][c2_]);
  }
}

// ====== k_prep2 (PROVEN r9): ctf/ctv from c2 ==========================================
__global__ void __launch_bounds__(512) k_prep2(
    const float* __restrict__ c2g, const float* __restrict__ bpW1,
    const float* __restrict__ bpb1, const float* __restrict__ dW1,
    const float* __restrict__ db1, float* __restrict__ ctf, float* __restrict__ ctv) {
  __shared__ float c2s[256], prf[256], prv[256];
  int b = blockIdx.x, t = threadIdx.x;
  if (t < 256) c2s[t] = c2g[b * 256 + t];
  __syncthreads();
  int col = t & 255, g = t >> 8;
  float af = 0.f, av = 0.f;
  #pragma unroll 4
  for (int k = g * 128; k < g * 128 + 128; k++) {
    float cv = c2s[k];
    af += cv * bpW1[(128 + k) * 256 + col];
    av += cv * dW1[(64 + k) * 256 + col];
  }
  if (g) { prf[col] = af; prv[col] = av; }
  __syncthreads();
  if (!g) {
    ctf[b * 256 + col] = af + prf[col] + bpb1[col];
    ctv[b * 256 + col] = av + prv[col] + db1[col];
  }
}

// ====== k_gc1 v2: fused ah1; float4 LDS reads (broadcast b128 + per-lane scalar) ======
__global__ void __launch_bounds__(512) k_gc1(
    const float* __restrict__ adj, const float* __restrict__ x,
    const float* __restrict__ W1, const float* __restrict__ b1,
    float* __restrict__ out) {
  __shared__ float adj_s[64 * 64];
  __shared__ float x_s[64 * 64];
  __shared__ float ax_s[64 * 64];
  __shared__ float h_s[64 * 64];
  int cg = blockIdx.x, b = blockIdx.y, t = threadIdx.x;
  const float* A = adj + b * 4096;
  const float* X = x + b * 4096;
  for (int e = t; e < 4096; e += 512) { adj_s[e] = A[e]; x_s[e] = X[e]; }
  __syncthreads();
  int c = t & 63, rg = t >> 6;
  // ax = adj @ x : adj_s rows via broadcast float4, x_s per-lane scalar
  {
    float acc[8];
    #pragma unroll
    for (int m = 0; m < 8; m++) acc[m] = 0.f;
    #pragma unroll 4
    for (int j4 = 0; j4 < 16; j4++) {
      float xv0 = x_s[(j4 * 4 + 0) * 64 + c];
      float xv1 = x_s[(j4 * 4 + 1) * 64 + c];
      float xv2 = x_s[(j4 * 4 + 2) * 64 + c];
      float xv3 = x_s[(j4 * 4 + 3) * 64 + c];
      #pragma unroll
      for (int m = 0; m < 8; m++) {
        float4 a4 = *(const float4*)&adj_s[(m * 8 + rg) * 64 + j4 * 4];
        acc[m] += a4.x * xv0 + a4.y * xv1 + a4.z * xv2 + a4.w * xv3;
      }
    }
    #pragma unroll
    for (int m = 0; m < 8; m++) ax_s[(m * 8 + rg) * 64 + c] = acc[m];
  }
  __syncthreads();
  // h = relu(ax @ W1[:, cg*64..] + b1) : ax_s broadcast float4, W1 per-lane global
  {
    float bv = b1[cg * 64 + c];
    float acc[8];
    #pragma unroll
    for (int m = 0; m < 8; m++) acc[m] = bv;
    #pragma unroll 4
    for (int k4 = 0; k4 < 16; k4++) {
      float w0 = W1[(k4 * 4 + 0) * 256 + cg * 64 + c];
      float w1 = W1[(k4 * 4 + 1) * 256 + cg * 64 + c];
      float w2 = W1[(k4 * 4 + 2) * 256 + cg * 64 + c];
      float w3 = W1[(k4 * 4 + 3) * 256 + cg * 64 + c];
      #pragma unroll
      for (int m = 0; m < 8; m++) {
        float4 a4 = *(const float4*)&ax_s[(m * 8 + rg) * 64 + k4 * 4];
        acc[m] += a4.x * w0 + a4.y * w1 + a4.z * w2 + a4.w * w3;
      }
    }
    #pragma unroll
    for (int m = 0; m < 8; m++) h_s[(m * 8 + rg) * 64 + c] = fmaxf(acc[m], 0.f);
  }
  __syncthreads();
  // out = adj @ h
  {
    float acc[8];
    #pragma unroll
    for (int m = 0; m < 8; m++) acc[m] = 0.f;
    #pragma unroll 4
    for (int j4 = 0; j4 < 16; j4++) {
      float h0 = h_s[(j4 * 4 + 0) * 64 + c];
      float h1 = h_s[(j4 * 4 + 1) * 64 + c];
      float h2 = h_s[(j4 * 4 + 2) * 64 + c];
      float h3 = h_s[(j4 * 4 + 3) * 64 + c];
      #pragma unroll
      for (int m = 0; m < 8; m++) {
        float4 a4 = *(const float4*)&adj_s[(m * 8 + rg) * 64 + j4 * 4];
        acc[m] += a4.x * h0 + a4.y * h1 + a4.z * h2 + a4.w * h3;
      }
    }
    float* O = out + b * 64 * 256 + cg * 64;
    #pragma unroll
    for (int m = 0; m < 8; m++) O[(m * 8 + rg) * 256 + c] = acc[m];
  }
}

// ====== k_linadj v2: fused ah2; float4 LDS reads =====================================
__global__ void __launch_bounds__(512) k_linadj(
    const float* __restrict__ adj, const float* __restrict__ in,
    const float* __restrict__ W, const float* __restrict__ bias,
    float* __restrict__ out) {
  __shared__ float adj_s[64 * 64];
  __shared__ float in_s[32 * 256];
  __shared__ float h_s[64 * 64];
  int cg = blockIdx.x, b = blockIdx.y, t = threadIdx.x;
  const float* A = adj + b * 4096;
  for (int e = t; e < 4096; e += 512) adj_s[e] = A[e];
  int c = t & 63, rg = t >> 6;
  float bv = bias[cg * 64 + c];
  #pragma unroll
  for (int half = 0; half < 2; half++) {
    if (half) __syncthreads();
    const float* I = in + (b * 64 + half * 32) * 256;
    for (int e = t; e < 32 * 256; e += 512) in_s[e] = I[e];
    __syncthreads();
    float acc[4];
    #pragma unroll
    for (int m = 0; m < 4; m++) acc[m] = bv;
    #pragma unroll 4
    for (int k4 = 0; k4 < 64; k4++) {
      float w0 = W[(k4 * 4 + 0) * 256 + cg * 64 + c];
      float w1 = W[(k4 * 4 + 1) * 256 + cg * 64 + c];
      float w2 = W[(k4 * 4 + 2) * 256 + cg * 64 + c];
      float w3 = W[(k4 * 4 + 3) * 256 + cg * 64 + c];
      #pragma unroll
      for (int m = 0; m < 4; m++) {
        float4 i4 = *(const float4*)&in_s[(m * 8 + rg) * 256 + k4 * 4];
        acc[m] += i4.x * w0 + i4.y * w1 + i4.z * w2 + i4.w * w3;
      }
    }
    #pragma unroll
    for (int m = 0; m < 4; m++)
      h_s[(half * 32 + m * 8 + rg) * 64 + c] = fmaxf(acc[m], 0.f);
  }
  __syncthreads();
  {
    float acc[8];
    #pragma unroll
    for (int m = 0; m < 8; m++) acc[m] = 0.f;
    #pragma unroll 4
    for (int j4 = 0; j4 < 16; j4++) {
      float h0 = h_s[(j4 * 4 + 0) * 64 + c];
      float h1 = h_s[(j4 * 4 + 1) * 64 + c];
      float h2 = h_s[(j4 * 4 + 2) * 64 + c];
      float h3 = h_s[(j4 * 4 + 3) * 64 + c];
      #pragma unroll
      for (int m = 0; m < 8; m++) {
        float4 a4 = *(const float4*)&adj_s[(m * 8 + rg) * 64 + j4 * 4];
        acc[m] += a4.x * h0 + a4.y * h1 + a4.z * h2 + a4.w * h3;
      }
    }
    float* O = out + b * 64 * 256 + cg * 64;
    #pragma unroll
    for (int m = 0; m < 8; m++) O[(m * 8 + rg) * 256 + c] = acc[m];
  }
}

// ---------------- mu / logvar heads v2: float4 LDS reads ------------------------------
__global__ void k_mulv(const float* __restrict__ in, const float* __restrict__ Wmu,
                       const float* __restrict__ bmu, const float* __restrict__ Wlv,
                       const float* __restrict__ blv, float* __restrict__ mu_out,
                       float* __restrict__ lv_out) {
  __shared__ float in_s[16 * 256];
  __shared__ float part[8 * 16 * 64];
  int t = threadIdx.x, r0 = blockIdx.x * 16;
  for (int e = t; e < 4096; e += 512) in_s[e] = in[r0 * 256 + e];
  __syncthreads();
  int c = t & 63, g = t >> 6;
  int sel = g >> 2, kq = g & 3;
  const float* W = sel ? Wlv : Wmu;
  float acc[16];
  #pragma unroll
  for (int r = 0; r < 16; r++) acc[r] = 0.f;
  #pragma unroll 2
  for (int k4 = kq * 16; k4 < kq * 16 + 16; k4++) {
    float w0 = W[(k4 * 4 + 0) * 64 + c];
    float w1 = W[(k4 * 4 + 1) * 64 + c];
    float w2 = W[(k4 * 4 + 2) * 64 + c];
    float w3 = W[(k4 * 4 + 3) * 64 + c];
    #pragma unroll
    for (int r = 0; r < 16; r++) {
      float4 i4 = *(const float4*)&in_s[r * 256 + k4 * 4];
      acc[r] += i4.x * w0 + i4.y * w1 + i4.z * w2 + i4.w * w3;
    }
  }
  #pragma unroll
  for (int r = 0; r < 16; r++) part[(g * 16 + r) * 64 + c] = acc[r];
  __syncthreads();
  if (t < 128) {
    int cc = t & 63, s2 = t >> 6;
    const float* bb = s2 ? blv : bmu;
    float* O = s2 ? lv_out : mu_out;
    float bv = bb[cc];
    #pragma unroll
    for (int r = 0; r < 16; r++) {
      float v = bv;
      #pragma unroll
      for (int q = 0; q < 4; q++) v += part[((s2 * 4 + q) * 16 + r) * 64 + cc];
      O[(r0 + r) * 64 + cc] = v;
    }
  }
}

// =============== NT GEMM core (PROVEN r6-r9) ==========================================
template <int KK, int WU, int WV, bool UG, bool VG, int ULEN, int VLEN>
__device__ __forceinline__ void mmrun(const u16* __restrict__ Up, int Uoff,
                                      const u16* __restrict__ Vp, int Voff,
                                      const char* lds, int ut0, int vt0, int lr, int lk,
                                      f32x4 (&acc)[WU][WV]) {
  #pragma unroll
  for (int kk = 0; kk < KK; kk++) {
    short8 uf[WU], vf[WV];
    #pragma unroll
    for (int i = 0; i < WU; i++) {
      int row = (ut0 + i) * 16 + lr;
      if constexpr (UG) {
        uf[i] = *(const short8*)(Up + row * ULEN + kk * 32 + lk * 8);
      } else {
        int byt = Uoff + row * (ULEN * 2) + kk * 64 + lk * 16;
        byt ^= (row & 7) << 4;
        uf[i] = *(const short8*)(lds + byt);
      }
    }
    #pragma unroll
    for (int j = 0; j < WV; j++) {
      int row = (vt0 + j) * 16 + lr;
      if constexpr (VG) {
        vf[j] = *(const short8*)(Vp + row * VLEN + kk * 32 + lk * 8);
      } else {
        int byt = Voff + row * (VLEN * 2) + kk * 64 + lk * 16;
        byt ^= (row & 7) << 4;
        vf[j] = *(const short8*)(lds + byt);
      }
    }
    #pragma unroll
    for (int i = 0; i < WU; i++)
      #pragma unroll
      for (int j = 0; j < WV; j++)
        acc[i][j] = __builtin_amdgcn_mfma_f32_16x16x32_bf16(uf[i], vf[j], acc[i][j], 0, 0, 0);
  }
}

__device__ __forceinline__ void st64(char* lds, int off, int rowlen, int crow, int ccol0,
                                     float a0, float a1, float a2, float a3) {
  uint2 pk; pk.x = cvtpk(a0, a1); pk.y = cvtpk(a2, a3);
  int byt = off + crow * (rowlen * 2) + ccol0 * 2;
  byt ^= (crow & 7) << 4;
  *(uint2*)(lds + byt) = pk;
}

template <int WU, int WV>
__device__ __forceinline__ void zacc(f32x4 (&acc)[WU][WV]) {
  #pragma unroll
  for (int i = 0; i < WU; i++)
    #pragma unroll
    for (int j = 0; j < WV; j++) acc[i][j] = (f32x4){0.f, 0.f, 0.f, 0.f};
}

// =============== k_chain2 (PROVEN r6): decoder, bf16 MFMA =============================
__global__ void __launch_bounds__(1024) k_chain2(
    const u16* __restrict__ WB, const float* __restrict__ mu_g,
    const float* __restrict__ ctv, const float* __restrict__ ctf,
    const float* __restrict__ db2, const float* __restrict__ db3,
    const float* __restrict__ reb1, const float* __restrict__ reb2,
    float* __restrict__ af_out, float* __restrict__ val_out,
    float* __restrict__ P, float* __restrict__ Q) {
  __shared__ char L[65536];
  constexpr int S2 = 0, S3 = 32768;
  int b = blockIdx.x, t = threadIdx.x;
  int w = t >> 6, lane = t & 63, lr = lane & 15, lk = lane >> 4;

  {
    int r = t >> 4, c0 = (t & 15) * 4;
    float4 v = *(const float4*)(mu_g + ((b * 64 + r) * 64 + c0));
    st64(L, S3, 64, r, c0, v.x, v.y, v.z, v.w);
  }
  __syncthreads();
  {
    f32x4 a[2][2]; zacc(a);
    int ut0 = (w & 7) * 2, vt0 = (w >> 3) * 2;
    mmrun<2, 2, 2, true, false, 64, 64>(WB + ODW1A, 0, WB, S3, L, ut0, vt0, lr, lk, a);
    #pragma unroll
    for (int j = 0; j < 2; j++) {
      int crow = (vt0 + j) * 16 + lr;
      #pragma unroll
      for (int i = 0; i < 2; i++) {
        int cc = (ut0 + i) * 16 + lk * 4;
        float4 cv = *(const float4*)(ctv + b * 256 + cc);
        st64(L, S2, 256, crow, cc, fmaxf(a[i][j][0] + cv.x, 0.f), fmaxf(a[i][j][1] + cv.y, 0.f),
             fmaxf(a[i][j][2] + cv.z, 0.f), fmaxf(a[i][j][3] + cv.w, 0.f));
      }
    }
  }
  __syncthreads();
  {
    f32x4 a[2][2]; zacc(a);
    int ut0 = (w & 7) * 2, vt0 = (w >> 3) * 2;
    mmrun<8, 2, 2, true, false, 256, 256>(WB + ODW2, 0, WB, S2, L, ut0, vt0, lr, lk, a);
    #pragma unroll
    for (int j = 0; j < 2; j++) {
      int crow = (vt0 + j) * 16 + lr;
      #pragma unroll
      for (int i = 0; i < 2; i++) {
        int cc = (ut0 + i) * 16 + lk * 4;
        float4 bv = *(const float4*)(db2 + cc);
        st64(L, S3, 256, crow, cc, fmaxf(a[i][j][0] + bv.x, 0.f), fmaxf(a[i][j][1] + bv.y, 0.f),
             fmaxf(a[i][j][2] + bv.z, 0.f), fmaxf(a[i][j][3] + bv.w, 0.f));
      }
    }
  }
  __syncthreads();
  {
    f32x4 a[1][1]; zacc(a);
    int ut = w & 3, vt = w >> 2;
    mmrun<8, 1, 1, true, false, 256, 256>(WB + ODW3, 0, WB, S3, L, ut, vt, lr, lk, a);
    int crow = vt * 16 + lr, cc = ut * 16 + lk * 4;
    float4 bv = *(const float4*)(db3 + cc);
    float s0 = 1.f / (1.f + expf(-(a[0][0][0] + bv.x)));
    float s1 = 1.f / (1.f + expf(-(a[0][0][1] + bv.y)));
    float s2 = 1.f / (1.f + expf(-(a[0][0][2] + bv.z)));
    float s3 = 1.f / (1.f + expf(-(a[0][0][3] + bv.w)));
    *(float4*)(af_out + ((b * 64 + crow) * 64 + cc)) =
        make_float4(s0 * 0.125f, s1 * 0.125f, s2 * 0.125f, s3 * 0.125f);
    st64(L, S2, 64, crow, cc, s0, s1, s2, s3);
  }
  __syncthreads();
  {
    f32x4 a[2][4]; zacc(a);
    int ut0 = (w & 7) * 2;
    int sel = w >> 3;
    const u16* Up = WB + (sel ? OBPB : OBPA);
    mmrun<2, 2, 4, true, false, 64, 64>(Up, 0, WB, S2, L, ut0, 0, lr, lk, a);
    float* out = sel ? Q : P;
    #pragma unroll
    for (int i = 0; i < 2; i++) {
      int cc = (ut0 + i) * 16 + lk * 4;
      float4 cv = make_float4(0.f, 0.f, 0.f, 0.f);
      if (sel == 0) cv = *(const float4*)(ctf + b * 256 + cc);
      #pragma unroll
      for (int j = 0; j < 4; j++) {
        int crow = j * 16 + lr;
        *(float4*)(out + ((b * 64 + crow) * 256 + cc)) =
            make_float4(a[i][j][0] + cv.x, a[i][j][1] + cv.y, a[i][j][2] + cv.z, a[i][j][3] + cv.w);
      }
    }
  }
  {
    f32x4 a[2][2]; zacc(a);
    int ut0 = (w & 7) * 2, vt0 = (w >> 3) * 2;
    mmrun<2, 2, 2, true, false, 64, 64>(WB + OREW1, 0, WB, S2, L, ut0, vt0, lr, lk, a);
    #pragma unroll
    for (int j = 0; j < 2; j++) {
      int crow = (vt0 + j) * 16 + lr;
      #pragma unroll
      for (int i = 0; i < 2; i++) {
        int cc = (ut0 + i) * 16 + lk * 4;
        float4 bv = *(const float4*)(reb1 + cc);
        st64(L, S3, 256, crow, cc, fmaxf(a[i][j][0] + bv.x, 0.f), fmaxf(a[i][j][1] + bv.y, 0.f),
             fmaxf(a[i][j][2] + bv.z, 0.f), fmaxf(a[i][j][3] + bv.w, 0.f));
      }
    }
  }
  __syncthreads();
  if (w < 4) {
    f32x4 a[1][1]; zacc(a);
    mmrun<8, 1, 1, true, false, 256, 256>(WB + OREW2, 0, WB, S3, L, 0, w, lr, lk, a);
    if (lk == 0) {
      float4 rb = *(const float4*)reb2;
      float v0 = 4.f / (1.f + expf(-(a[0][0][0] + rb.x)));
      float v1 = 4.f / (1.f + expf(-(a[0][0][1] + rb.y)));
      float v2 = 4.f / (1.f + expf(-(a[0][0][2] + rb.z)));
      float v3 = 4.f / (1.f + expf(-(a[0][0][3] + rb.w)));
      *(float4*)(val_out + (b * 64 + w * 16 + lr) * 4) = make_float4(v0, v1, v2, v3);
    }
  }
}

// =============== fused bond MLP v5 (PROVEN r8/r9, 54us): 2 i-tiles, prefetch ==========
__global__ void __launch_bounds__(512, 4) k_bond(
    const float* __restrict__ P, const float* __restrict__ Q,
    const u16* __restrict__ W2T, const float* __restrict__ b2,
    const u16* __restrict__ W3Tx, const float* __restrict__ b3,
    float* __restrict__ bp_out) {
  __shared__ u16 G[2 * 64 * 256];  // 64 KB: two XOR-swizzled 64x256 bf16 tiles
  int flat = blockIdx.x;
  int xcd = flat & 7, rest = flat >> 3;
  int b = xcd * 8 + (rest >> 5);
  int i0 = (rest & 31) * 2;
  int t = threadIdx.x;
  int lane = t & 63, w = t >> 6;
  int lr = lane & 15, lk = lane >> 4;

  {
    int colg = t & 63, rq = t >> 6;
    const float* Pb = P + (b * 64 + i0) * 256 + colg * 4;
    float4 p0 = *(const float4*)(Pb);
    float4 p1 = *(const float4*)(Pb + 256);
    const float* Qb = Q + b * 64 * 256;
    #pragma unroll
    for (int r = rq * 8; r < rq * 8 + 8; r++) {
      float4 q4 = *(const float4*)(Qb + r * 256 + colg * 4);
      int byt = (r * 512 + colg * 8) ^ ((r & 7) << 4);
      uint2 pk0, pk1;
      pk0.x = cvtpk(fmaxf(p0.x + q4.x, 0.f), fmaxf(p0.y + q4.y, 0.f));
      pk0.y = cvtpk(fmaxf(p0.z + q4.z, 0.f), fmaxf(p0.w + q4.w, 0.f));
      pk1.x = cvtpk(fmaxf(p1.x + q4.x, 0.f), fmaxf(p1.y + q4.y, 0.f));
      pk1.y = cvtpk(fmaxf(p1.z + q4.z, 0.f), fmaxf(p1.w + q4.w, 0.f));
      *(uint2*)((char*)G + byt) = pk0;
      *(uint2*)((char*)G + 32768 + byt) = pk1;
    }
  }
  __syncthreads();

  f32x4 acc[2][2][4];
  #pragma unroll
  for (int tl = 0; tl < 2; tl++)
    #pragma unroll
    for (int ni = 0; ni < 2; ni++)
      #pragma unroll
      for (int mi = 0; mi < 4; mi++) acc[tl][ni][mi] = (f32x4){0.f, 0.f, 0.f, 0.f};

  const u16* Wl = W2T + (w * 32 + lr) * 256 + lk * 8;
  short8 bwc0 = *(const short8*)(Wl);
  short8 bwc1 = *(const short8*)(Wl + 16 * 256);
  for (int kk = 0; kk < 8; kk++) {
    int kn = (kk + 1) & 7;
    short8 bwn0 = *(const short8*)(Wl + kn * 32);
    short8 bwn1 = *(const short8*)(Wl + 16 * 256 + kn * 32);
    __builtin_amdgcn_s_setprio(1);
    #pragma unroll
    for (int mi = 0; mi < 4; mi++) {
      int row = mi * 16 + lr;
      int byt = (row * 512 + kk * 64 + lk * 16) ^ ((row & 7) << 4);
      short8 a0 = *(const short8*)((const char*)G + byt);
      short8 a1 = *(const short8*)((const char*)G + 32768 + byt);
      acc[0][0][mi] = __builtin_amdgcn_mfma_f32_16x16x32_bf16(bwc0, a0, acc[0][0][mi], 0, 0, 0);
      acc[1][0][mi] = __builtin_amdgcn_mfma_f32_16x16x32_bf16(bwc0, a1, acc[1][0][mi], 0, 0, 0);
      acc[0][1][mi] = __builtin_amdgcn_mfma_f32_16x16x32_bf16(bwc1, a0, acc[0][1][mi], 0, 0, 0);
      acc[1][1][mi] = __builtin_amdgcn_mfma_f32_16x16x32_bf16(bwc1, a1, acc[1][1][mi], 0, 0, 0);
    }
    __builtin_amdgcn_s_setprio(0);
    bwc0 = bwn0;
    bwc1 = bwn1;
  }
  __syncthreads();

  #pragma unroll
  for (int tl = 0; tl < 2; tl++)
    #pragma unroll
    for (int ni = 0; ni < 2; ni++) {
      int col0 = w * 32 + ni * 16 + lk * 4;
      float4 bb = *(const float4*)(b2 + col0);
      #pragma unroll
      for (int mi = 0; mi < 4; mi++) {
        int grow = mi * 16 + lr;
        uint2 pk;
        pk.x = cvtpk(fmaxf(acc[tl][ni][mi][0] + bb.x, 0.f), fmaxf(acc[tl][ni][mi][1] + bb.y, 0.f));
        pk.y = cvtpk(fmaxf(acc[tl][ni][mi][2] + bb.z, 0.f), fmaxf(acc[tl][ni][mi][3] + bb.w, 0.f));
        int byt = ((grow * 512 + col0 * 2) ^ ((grow & 7) << 4)) + tl * 32768;
        *(uint2*)((char*)G + byt) = pk;
      }
    }
  __syncthreads();

  f32x4 acc2[2][4];
  #pragma unroll
  for (int tl = 0; tl < 2; tl++)
    #pragma unroll
    for (int mi = 0; mi < 4; mi++) acc2[tl][mi] = (f32x4){0.f, 0.f, 0.f, 0.f};
  {
    short8 bw2 = *(const short8*)(W3Tx + lr * 256 + w * 32 + lk * 8);
    #pragma unroll
    for (int tl = 0; tl < 2; tl++)
      #pragma unroll
      for (int mi = 0; mi < 4; mi++) {
        int row = mi * 16 + lr;
        int byt = ((row * 512 + (w * 32 + lk * 8) * 2) ^ ((row & 7) << 4)) + tl * 32768;
        short8 a = *(const short8*)((const char*)G + byt);
        acc2[tl][mi] = __builtin_amdgcn_mfma_f32_16x16x32_bf16(a, bw2, acc2[tl][mi], 0, 0, 0);
      }
  }
  __syncthreads();
  float* pf = (float*)G;
  if (lr < 4) {
    #pragma unroll
    for (int tl = 0; tl < 2; tl++)
      #pragma unroll
      for (int mi = 0; mi < 4; mi++)
        #pragma unroll
        for (int rg = 0; rg < 4; rg++) {
          int row = mi * 16 + lk * 4 + rg;
          pf[tl * 8192 + (w * 64 + row) * 4 + lr] = acc2[tl][mi][rg];
        }
  }
  __syncthreads();

  {
    int tl = t >> 8, idx = t & 255;
    int r = idx >> 2, c = idx & 3;
    float lv = b3[c];
    #pragma unroll
    for (int wq = 0; wq < 8; wq++) lv += pf[tl * 8192 + (wq * 64 + r) * 4 + c];
    float m = fmaxf(lv, __shfl_xor(lv, 1));
    m = fmaxf(m, __shfl_xor(m, 2));
    float e = expf(lv - m);
    float s = e + __shfl_xor(e, 1);
    s += __shfl_xor(s, 2);
    bp_out[((b * 64 + i0 + tl) * 64 + r) * 4 + c] = e / s;
  }
}

extern "C" void kernel_launch(void* const* d_in, const int* in_sizes, int n_in,
                              void* d_out, int out_size, void* d_ws, size_t ws_size,
                              hipStream_t stream) {
  const float* x    = (const float*)d_in[0];
  const float* adj  = (const float*)d_in[1];
  const float* cnd  = (const float*)d_in[2];
  const float* gc1W = (const float*)d_in[3];
  const float* gc1b = (const float*)d_in[4];
  const float* gc2W = (const float*)d_in[5];
  const float* gc2b = (const float*)d_in[6];
  const float* gmuW = (const float*)d_in[7];
  const float* gmub = (const float*)d_in[8];
  const float* glvW = (const float*)d_in[9];
  const float* glvb = (const float*)d_in[10];
  const float* ceW1 = (const float*)d_in[11];
  const float* ceb1 = (const float*)d_in[12];
  const float* ceW2 = (const float*)d_in[13];
  const float* ceb2 = (const float*)d_in[14];
  const float* dW1  = (const float*)d_in[15];
  const float* db1  = (const float*)d_in[16];
  const float* dW2  = (const float*)d_in[17];
  const float* db2  = (const float*)d_in[18];
  const float* dW3  = (const float*)d_in[19];
  const float* db3  = (const float*)d_in[20];
  // d_in[21..24] (at_*) are dead: mean(softmax) == 1/8 exactly
  const float* bpW1 = (const float*)d_in[25];
  const float* bpb1 = (const float*)d_in[26];
  const float* bpW2 = (const float*)d_in[27];
  const float* bpb2 = (const float*)d_in[28];
  const float* bpW3 = (const float*)d_in[29];
  const float* bpb3 = (const float*)d_in[30];
  const float* reW1 = (const float*)d_in[31];
  const float* reb1 = (const float*)d_in[32];
  const float* reW2 = (const float*)d_in[33];
  const float* reb2 = (const float*)d_in[34];

  float* out = (float*)d_out;
  float* af_out  = out;            // [64,64,64]
  float* bp_out  = out + 262144;   // [64,64,64,4]
  float* val_out = out + 1310720;  // [64,64,4]
  float* mu_out  = out + 1327104;  // [64,64,64]
  float* lv_out  = out + 1589248;  // [64,64,64]

  float* ws   = (float*)d_ws;
  float* ctf  = ws;                 // 16384
  float* ctv  = ws + 16384;         // 16384
  float* c2g  = ws + 32768;         // 16384
  float* buf1 = ws + 49152;         // 1048576  (ah1)
  float* buf2 = buf1 + 1048576;     // 1048576  (P)
  float* buf3 = buf2 + 1048576;     // 1048576  (ah2; later Q)
  u16*   WB   = (u16*)(buf3 + 1048576);  // 221184 u16

  k_prep1<<<118, 512, 0, stream>>>(cnd, ceW1, ceb1, ceW2, ceb2, dW1, dW2, dW3,
                                   bpW1, bpW2, bpW3, reW1, reW2, c2g, WB);
  k_prep2<<<64, 512, 0, stream>>>(c2g, bpW1, bpb1, dW1, db1, ctf, ctv);
  k_gc1<<<dim3(4, 64), 512, 0, stream>>>(adj, x, gc1W, gc1b, buf1);        // ah1
  k_linadj<<<dim3(4, 64), 512, 0, stream>>>(adj, buf1, gc2W, gc2b, buf3);  // ah2
  k_mulv<<<256, 512, 0, stream>>>(buf3, gmuW, gmub, glvW, glvb, mu_out, lv_out);
  k_chain2<<<64, 1024, 0, stream>>>(WB, mu_out, ctv, ctf, db2, db3, reb1, reb2,
                                    af_out, val_out, buf2, buf3);          // P=buf2 Q=buf3
  k_bond<<<2048, 512, 0, stream>>>(buf2, buf3, WB + OW2T, bpb2, WB + OW3TX, bpb3, bp_out);
}

// Round 12
// 159.004 us; speedup vs baseline: 1.1378x; 1.0137x over previous
//
#include <hip/hip_runtime.h>

typedef short short8 __attribute__((ext_vector_type(8)));
typedef float f32x4 __attribute__((ext_vector_type(4)));
typedef unsigned short u16;
typedef unsigned int u32;

__device__ __forceinline__ u16 f2bf(float f) {
  union { float f; u32 u; } x; x.f = f;
  u32 u = x.u;
  u32 r = (u + 0x7FFFu + ((u >> 16) & 1u)) >> 16;
  return (u16)r;
}

__device__ __forceinline__ u32 cvtpk(float lo, float hi) {
  u32 r;
  asm("v_cvt_pk_bf16_f32 %0, %1, %2" : "=v"(r) : "v"(lo), "v"(hi));
  return r;
}

// ---- WB bf16-region offsets (u16 units) — decoder + bond weights only ----
#define OW2T   0        // bond W2^T      [256][256]
#define OW3TX  65536    // bond W3 padT   [16][256]
#define ODW1A  69632    // dW1[0:64]^T    [256][64]
#define ODW2   86016    // dW2^T          [256][256]
#define ODW3   151552   // dW3^T          [64][256]
#define OBPA   167936   // bpW1[0:64]^T   [256][64]  x0.125
#define OBPB   184320   // bpW1[64:128]^T [256][64]  x0.125
#define OREW1  200704   // reW1^T         [256][64]
#define OREW2  217088   // reW2 padT      [16][256]

// ====== k_prep (merged r12): cond c2+ctf+ctv (blocks 0..63) + transposes (64..117) ====
__global__ void __launch_bounds__(512) k_prep(
    const float* __restrict__ cnd, const float* __restrict__ ceW1,
    const float* __restrict__ ceb1, const float* __restrict__ ceW2,
    const float* __restrict__ ceb2, const float* __restrict__ bpW1,
    const float* __restrict__ bpb1, const float* __restrict__ dW1,
    const float* __restrict__ db1, const float* __restrict__ dW2,
    const float* __restrict__ dW3, const float* __restrict__ bpW2,
    const float* __restrict__ bpW3, const float* __restrict__ reW1,
    const float* __restrict__ reW2, float* __restrict__ ctf,
    float* __restrict__ ctv, u16* __restrict__ WB) {
  __shared__ float h[256], c2s[256], prf[256], prv[256];
  __shared__ float T[64][65];
  int bid = blockIdx.x, t = threadIdx.x;
  if (bid < 64) {
    int b = bid;
    if (t < 256) {
      float c0 = cnd[b * 2 + 0], c1 = cnd[b * 2 + 1];
      h[t] = fmaxf(c0 * ceW1[t] + c1 * ceW1[256 + t] + ceb1[t], 0.f);
    }
    __syncthreads();
    int col = t & 255, g = t >> 8;
    {
      float acc = 0.f;
      #pragma unroll 8
      for (int k = g * 128; k < g * 128 + 128; k++) acc += h[k] * ceW2[k * 256 + col];
      if (g) prf[col] = acc;
      __syncthreads();
      if (!g) c2s[col] = acc + prf[col] + ceb2[col];
    }
    __syncthreads();
    float af = 0.f, av = 0.f;
    #pragma unroll 4
    for (int k = g * 128; k < g * 128 + 128; k++) {
      float cv = c2s[k];
      af += cv * bpW1[(128 + k) * 256 + col];
      av += cv * dW1[(64 + k) * 256 + col];
    }
    if (g) { prf[col] = af; prv[col] = av; }
    __syncthreads();
    if (!g) {
      ctf[b * 256 + col] = af + prf[col] + bpb1[col];
      ctv[b * 256 + col] = av + prv[col] + db1[col];
    }
    return;
  }
  int mb = bid - 64;  // 0..53
  if (mb >= 52) {
    if (t < 256) {
      const float* s = (mb == 52) ? reW2 : bpW3;
      u16* d = WB + ((mb == 52) ? OREW2 : OW3TX);
      #pragma unroll
      for (int c = 0; c < 16; c++) {
        float v = (c < 4) ? s[t * 4 + c] : 0.f;
        d[c * 256 + t] = f2bf(v);
      }
    }
    return;
  }
  const float* src; u16* dst; int sld, dld, tr, tc; float sc = 1.f;
  if (mb < 4)       { src = dW1;           dst = WB + ODW1A; sld = 256; dld = 64;  tr = 0;            tc = mb;          }
  else if (mb < 20) { int e = mb - 4;  src = dW2;  dst = WB + ODW2; sld = 256; dld = 256; tr = e >> 2; tc = e & 3; }
  else if (mb < 24) { int e = mb - 20; src = dW3;  dst = WB + ODW3; sld = 64;  dld = 256; tr = e;      tc = 0;     }
  else if (mb < 28) { int e = mb - 24; src = bpW1; dst = WB + OBPA; sld = 256; dld = 64;  tr = 0;      tc = e; sc = 0.125f; }
  else if (mb < 32) { int e = mb - 28; src = bpW1 + 64 * 256; dst = WB + OBPB; sld = 256; dld = 64; tr = 0; tc = e; sc = 0.125f; }
  else if (mb < 36) { int e = mb - 32; src = reW1; dst = WB + OREW1; sld = 256; dld = 64; tr = 0;      tc = e;     }
  else              { int e = mb - 36; src = bpW2; dst = WB + OW2T; sld = 256; dld = 256; tr = e >> 2; tc = e & 3; }
  int rl = t >> 6, cl = t & 63;
  #pragma unroll
  for (int it = 0; it < 8; it++) {
    int r = it * 8 + rl;
    T[r][cl] = src[(tr * 64 + r) * sld + tc * 64 + cl] * sc;
  }
  __syncthreads();
  #pragma unroll
  for (int it = 0; it < 8; it++) {
    int c2_ = it * 8 + rl;
    dst[(tc * 64 + c2_) * dld + tr * 64 + cl] = f2bf(T[cl][c2_]);
  }
}

// ====== k_gc1 v2 (PROVEN r11): fused ah1; float4 LDS reads ============================
__global__ void __launch_bounds__(512) k_gc1(
    const float* __restrict__ adj, const float* __restrict__ x,
    const float* __restrict__ W1, const float* __restrict__ b1,
    float* __restrict__ out) {
  __shared__ float adj_s[64 * 64];
  __shared__ float x_s[64 * 64];
  __shared__ float ax_s[64 * 64];
  __shared__ float h_s[64 * 64];
  int cg = blockIdx.x, b = blockIdx.y, t = threadIdx.x;
  const float* A = adj + b * 4096;
  const float* X = x + b * 4096;
  for (int e = t; e < 4096; e += 512) { adj_s[e] = A[e]; x_s[e] = X[e]; }
  __syncthreads();
  int c = t & 63, rg = t >> 6;
  {
    float acc[8];
    #pragma unroll
    for (int m = 0; m < 8; m++) acc[m] = 0.f;
    #pragma unroll 4
    for (int j4 = 0; j4 < 16; j4++) {
      float xv0 = x_s[(j4 * 4 + 0) * 64 + c];
      float xv1 = x_s[(j4 * 4 + 1) * 64 + c];
      float xv2 = x_s[(j4 * 4 + 2) * 64 + c];
      float xv3 = x_s[(j4 * 4 + 3) * 64 + c];
      #pragma unroll
      for (int m = 0; m < 8; m++) {
        float4 a4 = *(const float4*)&adj_s[(m * 8 + rg) * 64 + j4 * 4];
        acc[m] += a4.x * xv0 + a4.y * xv1 + a4.z * xv2 + a4.w * xv3;
      }
    }
    #pragma unroll
    for (int m = 0; m < 8; m++) ax_s[(m * 8 + rg) * 64 + c] = acc[m];
  }
  __syncthreads();
  {
    float bv = b1[cg * 64 + c];
    float acc[8];
    #pragma unroll
    for (int m = 0; m < 8; m++) acc[m] = bv;
    #pragma unroll 4
    for (int k4 = 0; k4 < 16; k4++) {
      float w0 = W1[(k4 * 4 + 0) * 256 + cg * 64 + c];
      float w1 = W1[(k4 * 4 + 1) * 256 + cg * 64 + c];
      float w2 = W1[(k4 * 4 + 2) * 256 + cg * 64 + c];
      float w3 = W1[(k4 * 4 + 3) * 256 + cg * 64 + c];
      #pragma unroll
      for (int m = 0; m < 8; m++) {
        float4 a4 = *(const float4*)&ax_s[(m * 8 + rg) * 64 + k4 * 4];
        acc[m] += a4.x * w0 + a4.y * w1 + a4.z * w2 + a4.w * w3;
      }
    }
    #pragma unroll
    for (int m = 0; m < 8; m++) h_s[(m * 8 + rg) * 64 + c] = fmaxf(acc[m], 0.f);
  }
  __syncthreads();
  {
    float acc[8];
    #pragma unroll
    for (int m = 0; m < 8; m++) acc[m] = 0.f;
    #pragma unroll 4
    for (int j4 = 0; j4 < 16; j4++) {
      float h0 = h_s[(j4 * 4 + 0) * 64 + c];
      float h1 = h_s[(j4 * 4 + 1) * 64 + c];
      float h2 = h_s[(j4 * 4 + 2) * 64 + c];
      float h3 = h_s[(j4 * 4 + 3) * 64 + c];
      #pragma unroll
      for (int m = 0; m < 8; m++) {
        float4 a4 = *(const float4*)&adj_s[(m * 8 + rg) * 64 + j4 * 4];
        acc[m] += a4.x * h0 + a4.y * h1 + a4.z * h2 + a4.w * h3;
      }
    }
    float* O = out + b * 64 * 256 + cg * 64;
    #pragma unroll
    for (int m = 0; m < 8; m++) O[(m * 8 + rg) * 256 + c] = acc[m];
  }
}

// ====== k_linadj v2 (PROVEN r11): fused ah2; float4 LDS reads =========================
__global__ void __launch_bounds__(512) k_linadj(
    const float* __restrict__ adj, const float* __restrict__ in,
    const float* __restrict__ W, const float* __restrict__ bias,
    float* __restrict__ out) {
  __shared__ float adj_s[64 * 64];
  __shared__ float in_s[32 * 256];
  __shared__ float h_s[64 * 64];
  int cg = blockIdx.x, b = blockIdx.y, t = threadIdx.x;
  const float* A = adj + b * 4096;
  for (int e = t; e < 4096; e += 512) adj_s[e] = A[e];
  int c = t & 63, rg = t >> 6;
  float bv = bias[cg * 64 + c];
  #pragma unroll
  for (int half = 0; half < 2; half++) {
    if (half) __syncthreads();
    const float* I = in + (b * 64 + half * 32) * 256;
    for (int e = t; e < 32 * 256; e += 512) in_s[e] = I[e];
    __syncthreads();
    float acc[4];
    #pragma unroll
    for (int m = 0; m < 4; m++) acc[m] = bv;
    #pragma unroll 4
    for (int k4 = 0; k4 < 64; k4++) {
      float w0 = W[(k4 * 4 + 0) * 256 + cg * 64 + c];
      float w1 = W[(k4 * 4 + 1) * 256 + cg * 64 + c];
      float w2 = W[(k4 * 4 + 2) * 256 + cg * 64 + c];
      float w3 = W[(k4 * 4 + 3) * 256 + cg * 64 + c];
      #pragma unroll
      for (int m = 0; m < 4; m++) {
        float4 i4 = *(const float4*)&in_s[(m * 8 + rg) * 256 + k4 * 4];
        acc[m] += i4.x * w0 + i4.y * w1 + i4.z * w2 + i4.w * w3;
      }
    }
    #pragma unroll
    for (int m = 0; m < 4; m++)
      h_s[(half * 32 + m * 8 + rg) * 64 + c] = fmaxf(acc[m], 0.f);
  }
  __syncthreads();
  {
    float acc[8];
    #pragma unroll
    for (int m = 0; m < 8; m++) acc[m] = 0.f;
    #pragma unroll 4
    for (int j4 = 0; j4 < 16; j4++) {
      float h0 = h_s[(j4 * 4 + 0) * 64 + c];
      float h1 = h_s[(j4 * 4 + 1) * 64 + c];
      float h2 = h_s[(j4 * 4 + 2) * 64 + c];
      float h3 = h_s[(j4 * 4 + 3) * 64 + c];
      #pragma unroll
      for (int m = 0; m < 8; m++) {
        float4 a4 = *(const float4*)&adj_s[(m * 8 + rg) * 64 + j4 * 4];
        acc[m] += a4.x * h0 + a4.y * h1 + a4.z * h2 + a4.w * h3;
      }
    }
    float* O = out + b * 64 * 256 + cg * 64;
    #pragma unroll
    for (int m = 0; m < 8; m++) O[(m * 8 + rg) * 256 + c] = acc[m];
  }
}

// ---------------- mu / logvar heads v2 (PROVEN r11): float4 LDS reads -----------------
__global__ void k_mulv(const float* __restrict__ in, const float* __restrict__ Wmu,
                       const float* __restrict__ bmu, const float* __restrict__ Wlv,
                       const float* __restrict__ blv, float* __restrict__ mu_out,
                       float* __restrict__ lv_out) {
  __shared__ float in_s[16 * 256];
  __shared__ float part[8 * 16 * 64];
  int t = threadIdx.x, r0 = blockIdx.x * 16;
  for (int e = t; e < 4096; e += 512) in_s[e] = in[r0 * 256 + e];
  __syncthreads();
  int c = t & 63, g = t >> 6;
  int sel = g >> 2, kq = g & 3;
  const float* W = sel ? Wlv : Wmu;
  float acc[16];
  #pragma unroll
  for (int r = 0; r < 16; r++) acc[r] = 0.f;
  #pragma unroll 2
  for (int k4 = kq * 16; k4 < kq * 16 + 16; k4++) {
    float w0 = W[(k4 * 4 + 0) * 64 + c];
    float w1 = W[(k4 * 4 + 1) * 64 + c];
    float w2 = W[(k4 * 4 + 2) * 64 + c];
    float w3 = W[(k4 * 4 + 3) * 64 + c];
    #pragma unroll
    for (int r = 0; r < 16; r++) {
      float4 i4 = *(const float4*)&in_s[r * 256 + k4 * 4];
      acc[r] += i4.x * w0 + i4.y * w1 + i4.z * w2 + i4.w * w3;
    }
  }
  #pragma unroll
  for (int r = 0; r < 16; r++) part[(g * 16 + r) * 64 + c] = acc[r];
  __syncthreads();
  if (t < 128) {
    int cc = t & 63, s2 = t >> 6;
    const float* bb = s2 ? blv : bmu;
    float* O = s2 ? lv_out : mu_out;
    float bv = bb[cc];
    #pragma unroll
    for (int r = 0; r < 16; r++) {
      float v = bv;
      #pragma unroll
      for (int q = 0; q < 4; q++) v += part[((s2 * 4 + q) * 16 + r) * 64 + cc];
      O[(r0 + r) * 64 + cc] = v;
    }
  }
}

// =============== NT GEMM core (PROVEN r6-r11) =========================================
template <int KK, int WU, int WV, bool UG, bool VG, int ULEN, int VLEN>
__device__ __forceinline__ void mmrun(const u16* __restrict__ Up, int Uoff,
                                      const u16* __restrict__ Vp, int Voff,
                                      const char* lds, int ut0, int vt0, int lr, int lk,
                                      f32x4 (&acc)[WU][WV]) {
  #pragma unroll
  for (int kk = 0; kk < KK; kk++) {
    short8 uf[WU], vf[WV];
    #pragma unroll
    for (int i = 0; i < WU; i++) {
      int row = (ut0 + i) * 16 + lr;
      if constexpr (UG) {
        uf[i] = *(const short8*)(Up + row * ULEN + kk * 32 + lk * 8);
      } else {
        int byt = Uoff + row * (ULEN * 2) + kk * 64 + lk * 16;
        byt ^= (row & 7) << 4;
        uf[i] = *(const short8*)(lds + byt);
      }
    }
    #pragma unroll
    for (int j = 0; j < WV; j++) {
      int row = (vt0 + j) * 16 + lr;
      if constexpr (VG) {
        vf[j] = *(const short8*)(Vp + row * VLEN + kk * 32 + lk * 8);
      } else {
        int byt = Voff + row * (VLEN * 2) + kk * 64 + lk * 16;
        byt ^= (row & 7) << 4;
        vf[j] = *(const short8*)(lds + byt);
      }
    }
    #pragma unroll
    for (int i = 0; i < WU; i++)
      #pragma unroll
      for (int j = 0; j < WV; j++)
        acc[i][j] = __builtin_amdgcn_mfma_f32_16x16x32_bf16(uf[i], vf[j], acc[i][j], 0, 0, 0);
  }
}

__device__ __forceinline__ void st64(char* lds, int off, int rowlen, int crow, int ccol0,
                                     float a0, float a1, float a2, float a3) {
  uint2 pk; pk.x = cvtpk(a0, a1); pk.y = cvtpk(a2, a3);
  int byt = off + crow * (rowlen * 2) + ccol0 * 2;
  byt ^= (crow & 7) << 4;
  *(uint2*)(lds + byt) = pk;
}

template <int WU, int WV>
__device__ __forceinline__ void zacc(f32x4 (&acc)[WU][WV]) {
  #pragma unroll
  for (int i = 0; i < WU; i++)
    #pragma unroll
    for (int j = 0; j < WV; j++) acc[i][j] = (f32x4){0.f, 0.f, 0.f, 0.f};
}

// =============== k_chain2 (PROVEN r6): decoder, bf16 MFMA =============================
__global__ void __launch_bounds__(1024) k_chain2(
    const u16* __restrict__ WB, const float* __restrict__ mu_g,
    const float* __restrict__ ctv, const float* __restrict__ ctf,
    const float* __restrict__ db2, const float* __restrict__ db3,
    const float* __restrict__ reb1, const float* __restrict__ reb2,
    float* __restrict__ af_out, float* __restrict__ val_out,
    float* __restrict__ P, float* __restrict__ Q) {
  __shared__ char L[65536];
  constexpr int S2 = 0, S3 = 32768;
  int b = blockIdx.x, t = threadIdx.x;
  int w = t >> 6, lane = t & 63, lr = lane & 15, lk = lane >> 4;

  {
    int r = t >> 4, c0 = (t & 15) * 4;
    float4 v = *(const float4*)(mu_g + ((b * 64 + r) * 64 + c0));
    st64(L, S3, 64, r, c0, v.x, v.y, v.z, v.w);
  }
  __syncthreads();
  {
    f32x4 a[2][2]; zacc(a);
    int ut0 = (w & 7) * 2, vt0 = (w >> 3) * 2;
    mmrun<2, 2, 2, true, false, 64, 64>(WB + ODW1A, 0, WB, S3, L, ut0, vt0, lr, lk, a);
    #pragma unroll
    for (int j = 0; j < 2; j++) {
      int crow = (vt0 + j) * 16 + lr;
      #pragma unroll
      for (int i = 0; i < 2; i++) {
        int cc = (ut0 + i) * 16 + lk * 4;
        float4 cv = *(const float4*)(ctv + b * 256 + cc);
        st64(L, S2, 256, crow, cc, fmaxf(a[i][j][0] + cv.x, 0.f), fmaxf(a[i][j][1] + cv.y, 0.f),
             fmaxf(a[i][j][2] + cv.z, 0.f), fmaxf(a[i][j][3] + cv.w, 0.f));
      }
    }
  }
  __syncthreads();
  {
    f32x4 a[2][2]; zacc(a);
    int ut0 = (w & 7) * 2, vt0 = (w >> 3) * 2;
    mmrun<8, 2, 2, true, false, 256, 256>(WB + ODW2, 0, WB, S2, L, ut0, vt0, lr, lk, a);
    #pragma unroll
    for (int j = 0; j < 2; j++) {
      int crow = (vt0 + j) * 16 + lr;
      #pragma unroll
      for (int i = 0; i < 2; i++) {
        int cc = (ut0 + i) * 16 + lk * 4;
        float4 bv = *(const float4*)(db2 + cc);
        st64(L, S3, 256, crow, cc, fmaxf(a[i][j][0] + bv.x, 0.f), fmaxf(a[i][j][1] + bv.y, 0.f),
             fmaxf(a[i][j][2] + bv.z, 0.f), fmaxf(a[i][j][3] + bv.w, 0.f));
      }
    }
  }
  __syncthreads();
  {
    f32x4 a[1][1]; zacc(a);
    int ut = w & 3, vt = w >> 2;
    mmrun<8, 1, 1, true, false, 256, 256>(WB + ODW3, 0, WB, S3, L, ut, vt, lr, lk, a);
    int crow = vt * 16 + lr, cc = ut * 16 + lk * 4;
    float4 bv = *(const float4*)(db3 + cc);
    float s0 = 1.f / (1.f + expf(-(a[0][0][0] + bv.x)));
    float s1 = 1.f / (1.f + expf(-(a[0][0][1] + bv.y)));
    float s2 = 1.f / (1.f + expf(-(a[0][0][2] + bv.z)));
    float s3 = 1.f / (1.f + expf(-(a[0][0][3] + bv.w)));
    *(float4*)(af_out + ((b * 64 + crow) * 64 + cc)) =
        make_float4(s0 * 0.125f, s1 * 0.125f, s2 * 0.125f, s3 * 0.125f);
    st64(L, S2, 64, crow, cc, s0, s1, s2, s3);
  }
  __syncthreads();
  {
    f32x4 a[2][4]; zacc(a);
    int ut0 = (w & 7) * 2;
    int sel = w >> 3;
    const u16* Up = WB + (sel ? OBPB : OBPA);
    mmrun<2, 2, 4, true, false, 64, 64>(Up, 0, WB, S2, L, ut0, 0, lr, lk, a);
    float* out = sel ? Q : P;
    #pragma unroll
    for (int i = 0; i < 2; i++) {
      int cc = (ut0 + i) * 16 + lk * 4;
      float4 cv = make_float4(0.f, 0.f, 0.f, 0.f);
      if (sel == 0) cv = *(const float4*)(ctf + b * 256 + cc);
      #pragma unroll
      for (int j = 0; j < 4; j++) {
        int crow = j * 16 + lr;
        *(float4*)(out + ((b * 64 + crow) * 256 + cc)) =
            make_float4(a[i][j][0] + cv.x, a[i][j][1] + cv.y, a[i][j][2] + cv.z, a[i][j][3] + cv.w);
      }
    }
  }
  {
    f32x4 a[2][2]; zacc(a);
    int ut0 = (w & 7) * 2, vt0 = (w >> 3) * 2;
    mmrun<2, 2, 2, true, false, 64, 64>(WB + OREW1, 0, WB, S2, L, ut0, vt0, lr, lk, a);
    #pragma unroll
    for (int j = 0; j < 2; j++) {
      int crow = (vt0 + j) * 16 + lr;
      #pragma unroll
      for (int i = 0; i < 2; i++) {
        int cc = (ut0 + i) * 16 + lk * 4;
        float4 bv = *(const float4*)(reb1 + cc);
        st64(L, S3, 256, crow, cc, fmaxf(a[i][j][0] + bv.x, 0.f), fmaxf(a[i][j][1] + bv.y, 0.f),
             fmaxf(a[i][j][2] + bv.z, 0.f), fmaxf(a[i][j][3] + bv.w, 0.f));
      }
    }
  }
  __syncthreads();
  if (w < 4) {
    f32x4 a[1][1]; zacc(a);
    mmrun<8, 1, 1, true, false, 256, 256>(WB + OREW2, 0, WB, S3, L, 0, w, lr, lk, a);
    if (lk == 0) {
      float4 rb = *(const float4*)reb2;
      float v0 = 4.f / (1.f + expf(-(a[0][0][0] + rb.x)));
      float v1 = 4.f / (1.f + expf(-(a[0][0][1] + rb.y)));
      float v2 = 4.f / (1.f + expf(-(a[0][0][2] + rb.z)));
      float v3 = 4.f / (1.f + expf(-(a[0][0][3] + rb.w)));
      *(float4*)(val_out + (b * 64 + w * 16 + lr) * 4) = make_float4(v0, v1, v2, v3);
    }
  }
}

// ===== k_bond v7: 4 waves; wave owns 64 cols x both tiles (LDS sweeps halved) =========
__global__ void __launch_bounds__(256, 2) k_bond(
    const float* __restrict__ P, const float* __restrict__ Q,
    const u16* __restrict__ W2T, const float* __restrict__ b2,
    const u16* __restrict__ W3Tx, const float* __restrict__ b3,
    float* __restrict__ bp_out) {
  __shared__ u16 G[2 * 64 * 256];  // 64 KB: two XOR-swizzled 64x256 bf16 tiles
  int flat = blockIdx.x;
  int xcd = flat & 7, rest = flat >> 3;
  int b = xcd * 8 + (rest >> 5);
  int i0 = (rest & 31) * 2;
  int t = threadIdx.x;
  int lane = t & 63, w = t >> 6;  // w 0..3
  int lr = lane & 15, lk = lane >> 4;

  // ---- build both G tiles: 256 threads, 16 rows each ----
  {
    int colg = t & 63, rq = t >> 6;
    const float* Pb = P + (b * 64 + i0) * 256 + colg * 4;
    float4 p0 = *(const float4*)(Pb);
    float4 p1 = *(const float4*)(Pb + 256);
    const float* Qb = Q + b * 64 * 256;
    #pragma unroll
    for (int r = rq * 16; r < rq * 16 + 16; r++) {
      float4 q4 = *(const float4*)(Qb + r * 256 + colg * 4);
      int byt = (r * 512 + colg * 8) ^ ((r & 7) << 4);
      uint2 pk0, pk1;
      pk0.x = cvtpk(fmaxf(p0.x + q4.x, 0.f), fmaxf(p0.y + q4.y, 0.f));
      pk0.y = cvtpk(fmaxf(p0.z + q4.z, 0.f), fmaxf(p0.w + q4.w, 0.f));
      pk1.x = cvtpk(fmaxf(p1.x + q4.x, 0.f), fmaxf(p1.y + q4.y, 0.f));
      pk1.y = cvtpk(fmaxf(p1.z + q4.z, 0.f), fmaxf(p1.w + q4.w, 0.f));
      *(uint2*)((char*)G + byt) = pk0;
      *(uint2*)((char*)G + 32768 + byt) = pk1;
    }
  }
  __syncthreads();

  // ---- GEMM1: wave w owns cols [64w,64w+64); acc[tl][ni][mi]; bw reused over 8 a's ---
  f32x4 acc[2][4][4];
  #pragma unroll
  for (int tl = 0; tl < 2; tl++)
    #pragma unroll
    for (int ni = 0; ni < 4; ni++)
      #pragma unroll
      for (int mi = 0; mi < 4; mi++) acc[tl][ni][mi] = (f32x4){0.f, 0.f, 0.f, 0.f};

  const u16* Wl = W2T + (w * 64 + lr) * 256 + lk * 8;
  short8 bwc[4];
  #pragma unroll
  for (int ni = 0; ni < 4; ni++) bwc[ni] = *(const short8*)(Wl + ni * 16 * 256);
  for (int kk = 0; kk < 8; kk++) {
    int kn = (kk + 1) & 7;
    short8 bwn[4];
    #pragma unroll
    for (int ni = 0; ni < 4; ni++) bwn[ni] = *(const short8*)(Wl + ni * 16 * 256 + kn * 32);
    __builtin_amdgcn_s_setprio(1);
    #pragma unroll
    for (int mi = 0; mi < 4; mi++) {
      int row = mi * 16 + lr;
      int byt = (row * 512 + kk * 64 + lk * 16) ^ ((row & 7) << 4);
      short8 a0 = *(const short8*)((const char*)G + byt);
      short8 a1 = *(const short8*)((const char*)G + 32768 + byt);
      #pragma unroll
      for (int ni = 0; ni < 4; ni++) {
        acc[0][ni][mi] = __builtin_amdgcn_mfma_f32_16x16x32_bf16(bwc[ni], a0, acc[0][ni][mi], 0, 0, 0);
        acc[1][ni][mi] = __builtin_amdgcn_mfma_f32_16x16x32_bf16(bwc[ni], a1, acc[1][ni][mi], 0, 0, 0);
      }
    }
    __builtin_amdgcn_s_setprio(0);
    #pragma unroll
    for (int ni = 0; ni < 4; ni++) bwc[ni] = bwn[ni];
  }
  __syncthreads();

  // ---- writeback g2 (bias+relu) bf16 ----
  #pragma unroll
  for (int tl = 0; tl < 2; tl++)
    #pragma unroll
    for (int ni = 0; ni < 4; ni++) {
      int col0 = w * 64 + ni * 16 + lk * 4;
      float4 bb = *(const float4*)(b2 + col0);
      #pragma unroll
      for (int mi = 0; mi < 4; mi++) {
        int grow = mi * 16 + lr;
        uint2 pk;
        pk.x = cvtpk(fmaxf(acc[tl][ni][mi][0] + bb.x, 0.f), fmaxf(acc[tl][ni][mi][1] + bb.y, 0.f));
        pk.y = cvtpk(fmaxf(acc[tl][ni][mi][2] + bb.z, 0.f), fmaxf(acc[tl][ni][mi][3] + bb.w, 0.f));
        int byt = ((grow * 512 + col0 * 2) ^ ((grow & 7) << 4)) + tl * 32768;
        *(uint2*)((char*)G + byt) = pk;
      }
    }
  __syncthreads();

  // ---- GEMM2: wave w does K-slice [64w,64w+64) of both tiles ----
  f32x4 acc2[2][4];
  #pragma unroll
  for (int tl = 0; tl < 2; tl++)
    #pragma unroll
    for (int mi = 0; mi < 4; mi++) acc2[tl][mi] = (f32x4){0.f, 0.f, 0.f, 0.f};
  #pragma unroll
  for (int kk2 = 0; kk2 < 2; kk2++) {
    short8 bw2 = *(const short8*)(W3Tx + lr * 256 + w * 64 + kk2 * 32 + lk * 8);
    #pragma unroll
    for (int tl = 0; tl < 2; tl++)
      #pragma unroll
      for (int mi = 0; mi < 4; mi++) {
        int row = mi * 16 + lr;
        int kb = (w * 64 + kk2 * 32 + lk * 8) * 2;
        int byt = ((row * 512 + kb) ^ ((row & 7) << 4)) + tl * 32768;
        short8 a = *(const short8*)((const char*)G + byt);
        acc2[tl][mi] = __builtin_amdgcn_mfma_f32_16x16x32_bf16(a, bw2, acc2[tl][mi], 0, 0, 0);
      }
  }
  __syncthreads();  // G reads done; alias 8KB of G as float partials [tl][w][row][4]
  float* pf = (float*)G;
  if (lr < 4) {
    #pragma unroll
    for (int tl = 0; tl < 2; tl++)
      #pragma unroll
      for (int mi = 0; mi < 4; mi++)
        #pragma unroll
        for (int rg = 0; rg < 4; rg++) {
          int row = mi * 16 + lk * 4 + rg;
          pf[((tl * 4 + w) * 64 + row) * 4 + lr] = acc2[tl][mi][rg];
        }
  }
  __syncthreads();

  // ---- softmax: 256 threads, loop over tiles; sum 4 wave partials ----
  #pragma unroll
  for (int tl = 0; tl < 2; tl++) {
    int r = t >> 2, c = t & 3;
    float lv = b3[c];
    #pragma unroll
    for (int cq = 0; cq < 4; cq++) lv += pf[((tl * 4 + cq) * 64 + r) * 4 + c];
    float m = fmaxf(lv, __shfl_xor(lv, 1));
    m = fmaxf(m, __shfl_xor(m, 2));
    float e = expf(lv - m);
    float s = e + __shfl_xor(e, 1);
    s += __shfl_xor(s, 2);
    bp_out[((b * 64 + i0 + tl) * 64 + r) * 4 + c] = e / s;
  }
}

extern "C" void kernel_launch(void* const* d_in, const int* in_sizes, int n_in,
                              void* d_out, int out_size, void* d_ws, size_t ws_size,
                              hipStream_t stream) {
  const float* x    = (const float*)d_in[0];
  const float* adj  = (const float*)d_in[1];
  const float* cnd  = (const float*)d_in[2];
  const float* gc1W = (const float*)d_in[3];
  const float* gc1b = (const float*)d_in[4];
  const float* gc2W = (const float*)d_in[5];
  const float* gc2b = (const float*)d_in[6];
  const float* gmuW = (const float*)d_in[7];
  const float* gmub = (const float*)d_in[8];
  const float* glvW = (const float*)d_in[9];
  const float* glvb = (const float*)d_in[10];
  const float* ceW1 = (const float*)d_in[11];
  const float* ceb1 = (const float*)d_in[12];
  const float* ceW2 = (const float*)d_in[13];
  const float* ceb2 = (const float*)d_in[14];
  const float* dW1  = (const float*)d_in[15];
  const float* db1  = (const float*)d_in[16];
  const float* dW2  = (const float*)d_in[17];
  const float* db2  = (const float*)d_in[18];
  const float* dW3  = (const float*)d_in[19];
  const float* db3  = (const float*)d_in[20];
  // d_in[21..24] (at_*) are dead: mean(softmax) == 1/8 exactly
  const float* bpW1 = (const float*)d_in[25];
  const float* bpb1 = (const float*)d_in[26];
  const float* bpW2 = (const float*)d_in[27];
  const float* bpb2 = (const float*)d_in[28];
  const float* bpW3 = (const float*)d_in[29];
  const float* bpb3 = (const float*)d_in[30];
  const float* reW1 = (const float*)d_in[31];
  const float* reb1 = (const float*)d_in[32];
  const float* reW2 = (const float*)d_in[33];
  const float* reb2 = (const float*)d_in[34];

  float* out = (float*)d_out;
  float* af_out  = out;            // [64,64,64]
  float* bp_out  = out + 262144;   // [64,64,64,4]
  float* val_out = out + 1310720;  // [64,64,4]
  float* mu_out  = out + 1327104;  // [64,64,64]
  float* lv_out  = out + 1589248;  // [64,64,64]

  float* ws   = (float*)d_ws;
  float* ctf  = ws;                 // 16384
  float* ctv  = ws + 16384;         // 16384
  float* buf1 = ws + 49152;         // 1048576  (ah1)
  float* buf2 = buf1 + 1048576;     // 1048576  (P)
  float* buf3 = buf2 + 1048576;     // 1048576  (ah2; later Q)
  u16*   WB   = (u16*)(buf3 + 1048576);  // 221184 u16

  k_prep<<<118, 512, 0, stream>>>(cnd, ceW1, ceb1, ceW2, ceb2, bpW1, bpb1, dW1, db1,
                                  dW2, dW3, bpW2, bpW3, reW1, reW2, ctf, ctv, WB);
  k_gc1<<<dim3(4, 64), 512, 0, stream>>>(adj, x, gc1W, gc1b, buf1);        // ah1
  k_linadj<<<dim3(4, 64), 512, 0, stream>>>(adj, buf1, gc2W, gc2b, buf3);  // ah2
  k_mulv<<<256, 512, 0, stream>>>(buf3, gmuW, gmub, glvW, glvb, mu_out, lv_out);
  k_chain2<<<64, 1024, 0, stream>>>(WB, mu_out, ctv, ctf, db2, db3, reb1, reb2,
                                    af_out, val_out, buf2, buf3);          // P=buf2 Q=buf3
  k_bond<<<2048, 256, 0, stream>>>(buf2, buf3, WB + OW2T, bpb2, WB + OW3TX, bpb3, bp_out);
}